// Round 8
// baseline (1047.595 us; speedup 1.0000x reference)
//
#include <hip/hip_runtime.h>
#include <hip/hip_bf16.h>

#define L_SEQ 2048
#define NB    4
#define DM    512
#define NH    8
#define DK    64
#define DFF   2048
#define NSAMP 40
#define NGRID 100
#define PARTC 16      // key chunks per (b,h)
#define CKEY  128     // keys per chunk

typedef __attribute__((ext_vector_type(8))) short bf16x8;
typedef __attribute__((ext_vector_type(4))) float f32x4;

__device__ __forceinline__ unsigned rotl32(unsigned x, unsigned r){ return (x<<r)|(x>>(32u-r)); }
__device__ __forceinline__ float bf2f(ushort u){ return __uint_as_float(((unsigned)u)<<16); }
__device__ __forceinline__ ushort f2bf(float f){
  unsigned u = __float_as_uint(f);
  unsigned r = (u + 0x7fffu + ((u>>16)&1u)) >> 16;
  return (ushort)r;
}

// ---------------- threefry2x32 (JAX partitionable — verified) ----------------
__device__ __forceinline__ void threefry2x32(unsigned k0, unsigned k1, unsigned x0, unsigned x1,
                                             unsigned &o0, unsigned &o1){
  unsigned ks0=k0, ks1=k1, ks2=k0^k1^0x1BD11BDAu;
  x0 += ks0; x1 += ks1;
#define RND(r) { x0 += x1; x1 = rotl32(x1, r); x1 ^= x0; }
  RND(13u) RND(15u) RND(26u) RND(6u)   x0+=ks1; x1+=ks2+1u;
  RND(17u) RND(29u) RND(16u) RND(24u)  x0+=ks2; x1+=ks0+2u;
  RND(13u) RND(15u) RND(26u) RND(6u)   x0+=ks0; x1+=ks1+3u;
  RND(17u) RND(29u) RND(16u) RND(24u)  x0+=ks1; x1+=ks2+4u;
  RND(13u) RND(15u) RND(26u) RND(6u)   x0+=ks2; x1+=ks0+5u;
#undef RND
  o0=x0; o1=x1;
}

// ---------------- prep: 12 weight transposes + bias-cat + threefry idx ----------------
__global__ __launch_bounds__(256) void k_prep(
    const float* __restrict__ Wq, const float* __restrict__ Wk,
    const float* __restrict__ Wv, const float* __restrict__ Wo,
    const float* __restrict__ f1W, const float* __restrict__ f2W,
    const float* __restrict__ bq, const float* __restrict__ bk, const float* __restrict__ bv,
    ushort* __restrict__ wt, float* __restrict__ bcat, int* __restrict__ sidx)
{
  const size_t F1T=1048576, F2T=2097152, LSTR=3145728;
  int bid = blockIdx.x, t = threadIdx.x;
  if (bid >= 6145){
    int i = (bid-6145)*256 + t;
    const int total = L_SEQ*NSAMP;
    if (i < total){
      unsigned o0, o1;
      threefry2x32(0u, 42u, 0u, (unsigned)(total + i), o0, o1);
      sidx[i] = (int)((o0 ^ o1) & (unsigned)(L_SEQ-1));
    }
    return;
  }
  if (bid == 6144){
    for (int i=t; i<2*1536; i+=256){
      int l = i / 1536, r = i - l*1536;
      float v = (r<512) ? bq[l*DM+r] : (r<1024) ? bk[l*DM+r-512] : bv[l*DM+r-1024];
      bcat[i] = v;
    }
    return;
  }
  int l = bid >= 3072; bid -= l*3072;
  const float* src; ushort* dst; int K, N, tile;
  if (bid < 1024){
    int m = bid >> 8; tile = bid & 255;
    src = (m==0?Wq:m==1?Wk:m==2?Wv:Wo) + (size_t)l*DM*DM;
    dst = wt + (size_t)l*LSTR + (size_t)m*262144; K=DM; N=DM;
  } else if (bid < 2048){
    tile = bid-1024; src = f1W + (size_t)l*DM*DFF; dst = wt + (size_t)l*LSTR + F1T; K=DM; N=DFF;
  } else {
    tile = bid-2048; src = f2W + (size_t)l*DFF*DM; dst = wt + (size_t)l*LSTR + F2T; K=DFF; N=DM;
  }
  int ntn = N/32;
  int n0 = (tile % ntn)*32, k0 = (tile / ntn)*32;
  __shared__ float tl[32][33];
  int r = t >> 5, c = t & 31;
  for (int rr=r; rr<32; rr+=8) tl[rr][c] = src[(size_t)(k0+rr)*N + n0 + c];
  __syncthreads();
  for (int rr=r; rr<32; rr+=8)
    dst[(size_t)(n0+rr)*K + k0 + c] = f2bf(tl[c][rr]);
}

// ---------------- embedding (writes f32 x and bf16 xb) ----------------
__global__ __launch_bounds__(256) void k_embed(const int* __restrict__ tok,
    const float* __restrict__ x_enc, const float* __restrict__ x_mark,
    const float* __restrict__ embW, const float* __restrict__ convW,
    const float* __restrict__ timeW, const float* __restrict__ timeb,
    float* __restrict__ x, ushort* __restrict__ xb){
  int bl = blockIdx.x; int b = bl >> 11; int l = bl & (L_SEQ-1);
  __shared__ float xin[21];
  __shared__ float xm[4];
  int t = threadIdx.x;
  if (t < 21){
    int tt = t/7, i = t - tt*7;
    int ll = (l + tt - 1) & (L_SEQ-1);
    xin[t] = x_enc[((size_t)b*L_SEQ + ll)*7 + i];
  }
  if (t >= 32 && t < 36) xm[t-32] = x_mark[((size_t)b*L_SEQ + l)*4 + (t-32)];
  __syncthreads();
  int tk = tok[bl];
  #pragma unroll
  for (int rep=0; rep<2; rep++){
    int d = t + rep*256;
    float v = embW[(size_t)tk*DM + d];
    const float* w = convW + (size_t)d*21;
    float cv = 0.f;
    #pragma unroll
    for (int tt=0; tt<3; tt++)
      #pragma unroll
      for (int i=0; i<7; i++)
        cv = fmaf(xin[tt*7+i], w[i*3+tt], cv);
    v += cv;
    float tv = timeb[d];
    #pragma unroll
    for (int m=0; m<4; m++) tv = fmaf(xm[m], timeW[m*DM + d], tv);
    v += tv;
    int j = d >> 1;
    float div = expf((float)(2*j) * (-0.017988946039015984f));
    float ang = (float)l * div;
    v += (d & 1) ? cosf(ang) : sinf(ang);
    x[(size_t)bl*DM + d] = v;
    xb[(size_t)bl*DM + d] = f2bf(v);
  }
}

// ---------------- bf16 MFMA GEMM, 128x128 tile, BK=64, 4 waves (2x2) x 64x64 ----------------
enum { MG_ADD=0, MG_GELU_BF16=1, MG_QKV=2 };

__global__ __launch_bounds__(256) void k_mgemm(
    const ushort* __restrict__ A, const ushort* __restrict__ Bt,
    const float* __restrict__ bias, float* __restrict__ Cf,
    ushort* __restrict__ Cb, int M, int N, int K, int mode)
{
  __shared__ ushort As[128][64];
  __shared__ ushort Bs[128][64];
  int tid = threadIdx.x, lane = tid & 63, wid = tid >> 6;
  int m0 = blockIdx.y*128, n0 = blockIdx.x*128;
  int wr = wid >> 1, wc = wid & 1;
  f32x4 acc[4][4];
  #pragma unroll
  for (int i=0;i<4;i++)
    #pragma unroll
    for(int j=0;j<4;j++) acc[i][j] = (f32x4){0.f,0.f,0.f,0.f};

  int lrow = lane >> 3;            // 0..7
  int lcol = (lane & 7) * 8;       // element offset within 64-wide K tile

  for (int k0 = 0; k0 < K; k0 += 64){
    __syncthreads();
    #pragma unroll
    for (int t=0; t<4; t++){
      int inst = wid*4 + t;        // 16 wave-insts cover 128 rows (8 rows each)
      int row = inst*8 + lrow;
      __builtin_amdgcn_global_load_lds(
        (const __attribute__((address_space(1))) void*)(A + (size_t)(m0+row)*K + k0 + lcol),
        (__attribute__((address_space(3))) void*)(&As[inst*8][0]), 16, 0, 0);
      __builtin_amdgcn_global_load_lds(
        (const __attribute__((address_space(1))) void*)(Bt + (size_t)(n0+row)*K + k0 + lcol),
        (__attribute__((address_space(3))) void*)(&Bs[inst*8][0]), 16, 0, 0);
    }
    __syncthreads();
    #pragma unroll
    for (int kk=0; kk<2; kk++){
      bf16x8 af[4], bfv[4];
      int ko = kk*32 + (lane>>4)*8;
      #pragma unroll
      for (int i=0;i<4;i++) af[i]  = *(const bf16x8*)&As[wr*64 + i*16 + (lane&15)][ko];
      #pragma unroll
      for (int j=0;j<4;j++) bfv[j] = *(const bf16x8*)&Bs[wc*64 + j*16 + (lane&15)][ko];
      #pragma unroll
      for (int i=0;i<4;i++)
        #pragma unroll
        for (int j=0;j<4;j++)
          acc[i][j] = __builtin_amdgcn_mfma_f32_16x16x32_bf16(af[i], bfv[j], acc[i][j], 0,0,0);
    }
  }

  int fq = lane >> 4, fr = lane & 15;
  for (int i=0;i<4;i++){
    for (int j=0;j<4;j++){
      #pragma unroll
      for (int jj=0;jj<4;jj++){
        int r = m0 + wr*64 + i*16 + fq*4 + jj;
        int c = n0 + wc*64 + j*16 + fr;
        float v = acc[i][j][jj] + bias[c];
        if (mode == MG_ADD){
          Cf[(size_t)r*N + c] += v;
        } else if (mode == MG_GELU_BF16){
          float g = 0.5f*v*(1.f + erff(v*0.70710678118654752f));
          Cb[(size_t)r*N + c] = f2bf(g);
        } else {
          int b = r >> 11, l = r & (L_SEQ-1), m3 = c >> 9, hh = (c>>6)&7, d = c & 63;
          Cb[(size_t)m3*4194304 + (((size_t)b*NH + hh)*L_SEQ + l)*64 + d] = f2bf(v);
        }
      }
    }
  }
}

// ---------------- V mean: 2-stage ----------------
__global__ __launch_bounds__(256) void k_vmean1(const ushort* __restrict__ V, float* __restrict__ part){
  int blk = blockIdx.x;
  int bh = blk >> 5, ch = blk & 31;
  int t = threadIdx.x, d = t & 63, c = t >> 6;
  const ushort* Vb = V + (size_t)bh*L_SEQ*DK + (size_t)(ch*64 + c*16)*DK;
  float s = 0.f;
  #pragma unroll
  for (int r=0; r<16; r++) s += bf2f(Vb[r*DK + d]);
  __shared__ float red[256];
  red[t]=s; __syncthreads();
  if (t < 64) part[(size_t)blk*64 + t] = red[t]+red[t+64]+red[t+128]+red[t+192];
}
__global__ __launch_bounds__(64) void k_vmean2(const float* __restrict__ part, float* __restrict__ vmean){
  int bh = blockIdx.x, d = threadIdx.x;
  float s = 0.f;
  #pragma unroll
  for (int ch=0; ch<32; ch++) s += part[(size_t)(bh*32+ch)*64 + d];
  vmean[bh*64+d] = s * (1.f/(float)L_SEQ);
}

// ---------------- M-score: full-wave sample/dim decomposition ----------------
// wave = 1 query. lane: sg=lane>>3 (sample slot), dg=lane&7 (dim group).
// 5 iters x 8 samples; 16B K-fragment per lane per iter; butterfly reduce at end.
__global__ __launch_bounds__(256) void k_mscore(const ushort* __restrict__ Q, const ushort* __restrict__ Km,
    const int* __restrict__ idx, float* __restrict__ M){
  int wid = threadIdx.x >> 6, lane = threadIdx.x & 63;
  int g = blockIdx.x*4 + wid;          // bh*L + l
  int l = g & (L_SEQ-1), bh = g >> 11;
  int sg = lane >> 3, dg = lane & 7;

  // Q fragment (8 dims)
  bf16x8 qv = *(const bf16x8*)(Q + (size_t)g*64 + dg*8);
  float qf[8];
  #pragma unroll
  for (int e=0;e<8;e++) qf[e] = bf2f((ushort)qv[e]);

  // prefetch sample indices, then K fragments
  const int* ir = idx + l*NSAMP;
  int ki[5];
  #pragma unroll
  for (int i=0;i<5;i++) ki[i] = ir[i*8 + sg];
  const ushort* Kb = Km + (size_t)bh*L_SEQ*64;
  bf16x8 kv[5];
  #pragma unroll
  for (int i=0;i<5;i++) kv[i] = *(const bf16x8*)(Kb + (size_t)ki[i]*64 + dg*8);

  float mx = -INFINITY, sm = 0.f;
  #pragma unroll
  for (int i=0;i<5;i++){
    float d = 0.f;
    #pragma unroll
    for (int e=0;e<8;e++) d = fmaf(qf[e], bf2f((ushort)kv[i][e]), d);
    // reduce over dim groups (bits 0..2)
    #pragma unroll
    for (int off=1; off<8; off<<=1) d += __shfl_xor(d, off);
    mx = fmaxf(mx, d);
    sm += d;
  }
  // reduce over all lanes: max ok; sum counts each sample 8x
  #pragma unroll
  for (int off=1; off<64; off<<=1){
    mx = fmaxf(mx, __shfl_xor(mx, off));
    sm += __shfl_xor(sm, off);
  }
  if (lane==0) M[g] = mx - sm * (1.f/(8.f*(float)NSAMP));
}

// ---------------- top-40 per (b,h): single wave, register-resident ----------------
__global__ __launch_bounds__(64) void k_topk(const float* __restrict__ M, int* __restrict__ Mtop){
  int bh = blockIdx.x, lane = threadIdx.x;
  float v[32];
  #pragma unroll
  for (int s=0; s<32; s++) v[s] = M[(size_t)bh*L_SEQ + s*64 + lane];
  for (int sel=0; sel<NSAMP; sel++){
    float best = -INFINITY; int bs = 0;
    #pragma unroll
    for (int s=0; s<32; s++){
      if (v[s] > best){ best = v[s]; bs = s; }
    }
    int bidx = bs*64 + lane;
    #pragma unroll
    for (int off=1; off<64; off<<=1){
      float ov = __shfl_xor(best, off);
      int   oi = __shfl_xor(bidx, off);
      if (ov > best || (ov == best && oi < bidx)){ best = ov; bidx = oi; }
    }
    if (lane == 0) Mtop[bh*NSAMP + sel] = bidx;
    int cs = bidx >> 6, cl = bidx & 63;
    if (lane == cl){
      #pragma unroll
      for (int s=0; s<32; s++) if (s == cs) v[s] = -INFINITY;
    }
  }
}

// ---------------- ctx init = broadcast mean V ----------------
__global__ __launch_bounds__(256) void k_ctxfill(const float* __restrict__ vmean, ushort* __restrict__ ctx){
  int i = blockIdx.x*256 + threadIdx.x;
  int c = i & (DM-1);
  int b = i >> 20;
  int h = c >> 6, d = c & 63;
  ctx[i] = f2bf(vmean[((b<<3)+h)*64 + d]);
}

// ---------------- MFMA flash attention, stage 1: per-chunk partials ----------------
__global__ __launch_bounds__(256) void k_attn1(const ushort* __restrict__ Q, const ushort* __restrict__ K,
    const ushort* __restrict__ V, const int* __restrict__ Mtop,
    float* __restrict__ pm, float* __restrict__ ps, float* __restrict__ pO){
  int bid = blockIdx.x;
  int xcd = bid & 7, idx = bid >> 3;
  int bh = xcd*4 + (idx & 3), ch = idx >> 2;
  int l0 = ch * CKEY;
  int t = threadIdx.x, lane = t & 63, w = t >> 6;

  __shared__ ushort Qs[48][64];
  __shared__ ushort Ks[CKEY][64];
  __shared__ ushort Vs[CKEY][66];
  __shared__ ushort Ps[48][136];
  __shared__ float rmax[4][48];
  __shared__ float rsum[4][48];
  __shared__ float Oacc[48][64];
  __shared__ int qidx[48];

  if (t < 40) qidx[t] = Mtop[bh*NSAMP + t];
  const ushort* Kb = K + ((size_t)bh*L_SEQ + l0)*64;
  #pragma unroll
  for (int i=0;i<4;i++){
    int e = i*256 + t;
    __builtin_amdgcn_global_load_lds(
      (const __attribute__((address_space(1))) void*)(Kb + (size_t)e*8),
      (__attribute__((address_space(3))) void*)(&Ks[0][0] + (size_t)e*8), 16, 0, 0);
  }
  __syncthreads();

  const ushort* Qb = Q + (size_t)bh*L_SEQ*64;
  {
    int row = t >> 3, seg = t & 7;
    bf16x8 qv = *(const bf16x8*)(Qb + (size_t)qidx[row]*64 + seg*8);
    *(bf16x8*)&Qs[row][seg*8] = qv;
    if (t < 128){
      int r2 = 32 + (t>>3);
      bf16x8 z = (bf16x8){0,0,0,0,0,0,0,0};
      if (r2 < 40) z = *(const bf16x8*)(Qb + (size_t)qidx[r2]*64 + (t&7)*8);
      *(bf16x8*)&Qs[r2][(t&7)*8] = z;
    }
  }
  const ushort* Vb = V + ((size_t)bh*L_SEQ + l0)*64;
  #pragma unroll
  for (int i=0;i<4;i++){
    int e = i*256 + t;
    int row = e >> 3, seg = e & 7;
    bf16x8 vv = *(const bf16x8*)(Vb + (size_t)e*8);
    *(bf16x8*)&Vs[row][seg*8] = vv;
  }
  __syncthreads();

  for (int i=t; i<48*64; i+=256) ((float*)Oacc)[i] = 0.f;

  f32x4 sa[3][2];
  #pragma unroll
  for (int i=0;i<3;i++) for (int j=0;j<2;j++) sa[i][j] = (f32x4){0.f,0.f,0.f,0.f};
  #pragma unroll
  for (int ks=0; ks<2; ks++){
    int ko = ks*32 + (lane>>4)*8;
    bf16x8 af[3], bf[2];
    #pragma unroll
    for (int i=0;i<3;i++) af[i] = *(const bf16x8*)&Qs[i*16 + (lane&15)][ko];
    #pragma unroll
    for (int j=0;j<2;j++) bf[j] = *(const bf16x8*)&Ks[w*32 + j*16 + (lane&15)][ko];
    #pragma unroll
    for (int i=0;i<3;i++)
      #pragma unroll
      for (int j=0;j<2;j++)
        sa[i][j] = __builtin_amdgcn_mfma_f32_16x16x32_bf16(af[i], bf[j], sa[i][j], 0,0,0);
  }
  #pragma unroll
  for (int i=0;i<3;i++)
    #pragma unroll
    for (int j=0;j<2;j++)
      #pragma unroll
      for (int jj=0;jj<4;jj++) sa[i][j][jj] *= 0.125f;
  #pragma unroll
  for (int i=0;i<3;i++){
    #pragma unroll
    for (int jj=0;jj<4;jj++){
      float mx = fmaxf(sa[i][0][jj], sa[i][1][jj]);
      #pragma unroll
      for (int off=1; off<16; off<<=1) mx = fmaxf(mx, __shfl_xor(mx, off));
      if ((lane&15)==0) rmax[w][i*16 + (lane>>4)*4 + jj] = mx;
    }
  }
  __syncthreads();
  #pragma unroll
  for (int i=0;i<3;i++){
    #pragma unroll
    for (int jj=0;jj<4;jj++){
      int row = i*16 + (lane>>4)*4 + jj;
      float m = fmaxf(fmaxf(rmax[0][row], rmax[1][row]), fmaxf(rmax[2][row], rmax[3][row]));
      float p0 = __expf(sa[i][0][jj] - m);
      float p1 = __expf(sa[i][1][jj] - m);
      Ps[row][w*32 + (lane&15)]      = f2bf(p0);
      Ps[row][w*32 + 16 + (lane&15)] = f2bf(p1);
      float sm = p0 + p1;
      #pragma unroll
      for (int off=1; off<16; off<<=1) sm += __shfl_xor(sm, off);
      if ((lane&15)==0) rsum[w][row] = sm;
    }
  }
  __syncthreads();

  f32x4 oa[3][4];
  #pragma unroll
  for (int i=0;i<3;i++) for (int j=0;j<4;j++) oa[i][j] = (f32x4){0.f,0.f,0.f,0.f};
  {
    bf16x8 pa[3], vb[4];
    int kbase = w*32 + (lane>>4)*8;
    #pragma unroll
    for (int i=0;i<3;i++) pa[i] = *(const bf16x8*)&Ps[i*16 + (lane&15)][kbase];
    #pragma unroll
    for (int j=0;j<4;j++){
      #pragma unroll
      for (int e=0;e<8;e++) vb[j][e] = (short)Vs[kbase + e][j*16 + (lane&15)];
    }
    #pragma unroll
    for (int i=0;i<3;i++)
      #pragma unroll
      for (int j=0;j<4;j++)
        oa[i][j] = __builtin_amdgcn_mfma_f32_16x16x32_bf16(pa[i], vb[j], oa[i][j], 0,0,0);
  }
  #pragma unroll
  for (int ww=0; ww<4; ww++){
    if (w == ww){
      #pragma unroll
      for (int i=0;i<3;i++)
        #pragma unroll
        for (int j=0;j<4;j++)
          #pragma unroll
          for (int jj=0;jj<4;jj++)
            Oacc[i*16 + (lane>>4)*4 + jj][j*16 + (lane&15)] += oa[i][j][jj];
    }
    __syncthreads();
  }

  size_t base = ((size_t)bh*PARTC + ch);
  if (t < 40){
    float m = fmaxf(fmaxf(rmax[0][t], rmax[1][t]), fmaxf(rmax[2][t], rmax[3][t]));
    pm[base*40 + t] = m;
    ps[base*40 + t] = rsum[0][t]+rsum[1][t]+rsum[2][t]+rsum[3][t];
  }
  {
    int row = t >> 3, d0 = (t&7)*8;
    float* dst = pO + (base*48 + row)*64 + d0;
    #pragma unroll
    for (int e=0;e<8;e++) dst[e] = Oacc[row][d0+e];
    if (t < 64){
      int r2 = 32 + (t>>3);
      float* dst2 = pO + (base*48 + r2)*64 + d0;
      #pragma unroll
      for (int e=0;e<8;e++) dst2[e] = Oacc[r2][d0+e];
    }
  }
}

// ---------------- flash attention, stage 2: combine chunks, scatter to ctx ----------------
__global__ __launch_bounds__(256) void k_attn2(const float* __restrict__ pm, const float* __restrict__ ps,
    const float* __restrict__ pO, const int* __restrict__ Mtop, ushort* __restrict__ ctx){
  int bh = blockIdx.x, b = bh >> 3, h = bh & 7;
  int t = threadIdx.x;
  __shared__ float wch[PARTC][40];
  __shared__ float inv_s[40];
  __shared__ int qidx[40];
  if (t < 40){
    qidx[t] = Mtop[bh*NSAMP + t];
    float m = -INFINITY;
    #pragma unroll
    for (int c=0;c<PARTC;c++) m = fmaxf(m, pm[((size_t)bh*PARTC + c)*40 + t]);
    float s = 0.f;
    #pragma unroll
    for (int c=0;c<PARTC;c++){
      float wc = __expf(pm[((size_t)bh*PARTC + c)*40 + t] - m);
      wch[c][t] = wc;
      s += wc * ps[((size_t)bh*PARTC + c)*40 + t];
    }
    inv_s[t] = 1.f / s;
  }
  __syncthreads();
  #pragma unroll
  for (int iter=0; iter<2; iter++){
    int row = iter*32 + (t>>3);
    if (row < 40){
      int d0 = (t&7)*8;
      float o[8] = {0.f,0.f,0.f,0.f,0.f,0.f,0.f,0.f};
      for (int c=0;c<PARTC;c++){
        const float* pp = pO + (((size_t)bh*PARTC + c)*48 + row)*64 + d0;
        float wc = wch[c][row];
        float4 a = *(const float4*)pp, b4 = *(const float4*)(pp+4);
        o[0]=fmaf(wc,a.x,o[0]); o[1]=fmaf(wc,a.y,o[1]); o[2]=fmaf(wc,a.z,o[2]); o[3]=fmaf(wc,a.w,o[3]);
        o[4]=fmaf(wc,b4.x,o[4]); o[5]=fmaf(wc,b4.y,o[5]); o[6]=fmaf(wc,b4.z,o[6]); o[7]=fmaf(wc,b4.w,o[7]);
      }
      float is = inv_s[row];
      bf16x8 wv;
      #pragma unroll
      for (int e=0;e<8;e++) wv[e] = (short)f2bf(o[e]*is);
      *(bf16x8*)(ctx + ((size_t)b*L_SEQ + qidx[row])*DM + h*64 + d0) = wv;
    }
  }
}

// ---------------- LayerNorm: one wave per row ----------------
__global__ __launch_bounds__(256) void k_ln(float* __restrict__ x,
    const float* __restrict__ g, const float* __restrict__ b,
    ushort* __restrict__ xb){
  int row = blockIdx.x*4 + (threadIdx.x>>6);
  int lane = threadIdx.x & 63;
  float* xr = x + (size_t)row*DM + lane*8;
  float4 v0 = *(const float4*)(xr);
  float4 v1 = *(const float4*)(xr + 4);
  float s = v0.x+v0.y+v0.z+v0.w+v1.x+v1.y+v1.z+v1.w;
  #pragma unroll
  for (int off=1; off<64; off<<=1) s += __shfl_xor(s, off);
  float mu = s * (1.f/(float)DM);
  float d0=v0.x-mu, d1=v0.y-mu, d2=v0.z-mu, d3=v0.w-mu;
  float d4=v1.x-mu, d5=v1.y-mu, d6=v1.z-mu, d7=v1.w-mu;
  float q = d0*d0+d1*d1+d2*d2+d3*d3+d4*d4+d5*d5+d6*d6+d7*d7;
  #pragma unroll
  for (int off=1; off<64; off<<=1) q += __shfl_xor(q, off);
  float r = rsqrtf(q * (1.f/(float)DM) + 1e-5f);
  float4 g0 = *(const float4*)(g + lane*8);
  float4 g1 = *(const float4*)(g + lane*8 + 4);
  float4 b0 = *(const float4*)(b + lane*8);
  float4 b1 = *(const float4*)(b + lane*8 + 4);
  float o0=d0*r*g0.x+b0.x, o1=d1*r*g0.y+b0.y, o2=d2*r*g0.z+b0.z, o3=d3*r*g0.w+b0.w;
  float o4=d4*r*g1.x+b1.x, o5=d5*r*g1.y+b1.y, o6=d6*r*g1.z+b1.z, o7=d7*r*g1.w+b1.w;
  *(float4*)(xr)     = (float4){o0,o1,o2,o3};
  *(float4*)(xr + 4) = (float4){o4,o5,o6,o7};
  if (xb){
    bf16x8 w;
    w[0]=(short)f2bf(o0); w[1]=(short)f2bf(o1); w[2]=(short)f2bf(o2); w[3]=(short)f2bf(o3);
    w[4]=(short)f2bf(o4); w[5]=(short)f2bf(o5); w[6]=(short)f2bf(o6); w[7]=(short)f2bf(o7);
    *(bf16x8*)(xb + (size_t)row*DM + lane*8) = w;
  }
}

// ---------------- final logits ----------------
__global__ __launch_bounds__(64) void k_logits(const float* __restrict__ x, const float* __restrict__ embW,
                                               float* __restrict__ out){
  int bid = blockIdx.x;
  int b = bid / NGRID, g = bid - b*NGRID;
  const float* xr = x + ((size_t)b*L_SEQ + (L_SEQ-1))*DM;
  const float* er = embW + (size_t)g*DM;
  int lane = threadIdx.x;
  float s = 0.f;
  for (int d=lane; d<DM; d+=64) s = fmaf(xr[d], er[d], s);
  for (int off=32; off; off>>=1) s += __shfl_xor(s, off);
  if (lane==0) out[bid] = s;
}

extern "C" void kernel_launch(void* const* d_in, const int* in_sizes, int n_in,
                              void* d_out, int out_size, void* d_ws, size_t ws_size,
                              hipStream_t stream) {
  const int*   tok    = (const int*)d_in[0];
  const float* x_enc  = (const float*)d_in[1];
  const float* x_mark = (const float*)d_in[2];
  const float* embW   = (const float*)d_in[3];
  const float* convW  = (const float*)d_in[4];
  const float* timeW  = (const float*)d_in[5];
  const float* timeb  = (const float*)d_in[6];
  const float* Wq = (const float*)d_in[7];  const float* bq = (const float*)d_in[8];
  const float* Wk = (const float*)d_in[9];  const float* bk = (const float*)d_in[10];
  const float* Wv = (const float*)d_in[11]; const float* bv = (const float*)d_in[12];
  const float* Wo = (const float*)d_in[13]; const float* bo = (const float*)d_in[14];
  const float* ln1g = (const float*)d_in[15]; const float* ln1b = (const float*)d_in[16];
  const float* ln2g = (const float*)d_in[17]; const float* ln2b = (const float*)d_in[18];
  const float* f1W = (const float*)d_in[19]; const float* f1b = (const float*)d_in[20];
  const float* f2W = (const float*)d_in[21]; const float* f2b = (const float*)d_in[22];
  const float* nrmg = (const float*)d_in[23]; const float* nrmb = (const float*)d_in[24];
  float* out = (float*)d_out;

  char* ws = (char*)d_ws;
  float*  x    = (float*) (ws);                       // 16 MB f32 residual
  ushort* xb   = (ushort*)(ws + ((size_t)16<<20));    //  8 MB bf16 GEMM input
  ushort* q    = (ushort*)(ws + ((size_t)24<<20));    //  8 MB (B,H,L,64); k,v follow
  ushort* kbuf = (ushort*)(ws + ((size_t)32<<20));
  ushort* vbuf = (ushort*)(ws + ((size_t)40<<20));
  ushort* ctx  = (ushort*)(ws + ((size_t)48<<20));    //  8 MB
  ushort* hbuf = (ushort*)(ws + ((size_t)24<<20));    // 32 MB, overlays q/k/v/ctx
  ushort* wt   = (ushort*)(ws + ((size_t)56<<20));    // 12 MB bf16 weights^T
  float*  Mbuf = (float*) (ws + ((size_t)69<<20));
  int*    Mtop = (int*)   (ws + ((size_t)70<<20));
  int*    sidx = (int*)   (ws + ((size_t)71<<20));
  float*  vmean= (float*) (ws + ((size_t)72<<20));
  float*  bcat = (float*) (ws + ((size_t)73<<20));
  float*  part = (float*) (ws + ((size_t)74<<20));
  float*  pO   = (float*) (ws + ((size_t)75<<20));    // 6.3 MB
  float*  pmb  = (float*) (ws + ((size_t)82<<20));
  float*  psb  = (float*) (ws + ((size_t)82<<20) + 102400);

  const int Mrows = NB*L_SEQ;   // 8192
  const size_t WQT=0, WOT=786432, F1T=1048576, F2T=2097152, LSTR=3145728;

  k_prep<<<6465, 256, 0, stream>>>(Wq, Wk, Wv, Wo, f1W, f2W, bq, bk, bv, wt, bcat, sidx);
  k_embed<<<NB*L_SEQ, 256, 0, stream>>>(tok, x_enc, x_mark, embW, convW, timeW, timeb, x, xb);

  for (int l=0; l<2; l++){
    size_t b5 = (size_t)l*DM;
    ushort* wl = wt + (size_t)l*LSTR;

    k_mgemm<<<dim3(1536/128, Mrows/128), 256, 0, stream>>>(xb, wl+WQT, bcat+l*1536, nullptr, q, Mrows, 1536, DM, MG_QKV);
    k_vmean1<<<NB*NH*32, 256, 0, stream>>>(vbuf, part);
    k_vmean2<<<NB*NH, 64, 0, stream>>>(part, vmean);
    k_mscore<<<NB*NH*L_SEQ/4, 256, 0, stream>>>(q, kbuf, sidx, Mbuf);
    k_topk<<<NB*NH, 64, 0, stream>>>(Mbuf, Mtop);
    k_ctxfill<<<(NB*L_SEQ*DM)/256, 256, 0, stream>>>(vmean, ctx);
    k_attn1<<<NB*NH*PARTC, 256, 0, stream>>>(q, kbuf, vbuf, Mtop, pmb, psb, pO);
    k_attn2<<<NB*NH, 256, 0, stream>>>(pmb, psb, pO, Mtop, ctx);
    k_mgemm<<<dim3(DM/128, Mrows/128), 256, 0, stream>>>(ctx, wl+WOT, bo+b5, x, nullptr, Mrows, DM, DM, MG_ADD);
    k_ln<<<Mrows/4, 256, 0, stream>>>(x, ln1g+b5, ln1b+b5, xb);
    k_mgemm<<<dim3(DFF/128, Mrows/128), 256, 0, stream>>>(xb, wl+F1T, f1b + (size_t)l*DFF, nullptr, hbuf, Mrows, DFF, DM, MG_GELU_BF16);
    k_mgemm<<<dim3(DM/128, Mrows/128), 256, 0, stream>>>(hbuf, wl+F2T, f2b+b5, x, nullptr, Mrows, DM, DFF, MG_ADD);
    k_ln<<<Mrows/4, 256, 0, stream>>>(x, ln2g+b5, ln2b+b5, xb);
  }
  k_ln<<<Mrows/4, 256, 0, stream>>>(x, nrmg, nrmb, nullptr);
  k_logits<<<NB*NGRID, 64, 0, stream>>>(x, embW, out);
}

// Round 9
// 548.879 us; speedup vs baseline: 1.9086x; 1.9086x over previous
//
#include <hip/hip_runtime.h>
#include <hip/hip_bf16.h>

#define L_SEQ 2048
#define NB    4
#define DM    512
#define NH    8
#define DK    64
#define DFF   2048
#define NSAMP 40
#define NGRID 100
#define PARTC 16      // key chunks per (b,h)
#define CKEY  128     // keys per chunk

typedef __attribute__((ext_vector_type(8))) short bf16x8;
typedef __attribute__((ext_vector_type(4))) float f32x4;

__device__ __forceinline__ unsigned rotl32(unsigned x, unsigned r){ return (x<<r)|(x>>(32u-r)); }
__device__ __forceinline__ float bf2f(ushort u){ return __uint_as_float(((unsigned)u)<<16); }
__device__ __forceinline__ ushort f2bf(float f){
  unsigned u = __float_as_uint(f);
  unsigned r = (u + 0x7fffu + ((u>>16)&1u)) >> 16;
  return (ushort)r;
}

// ---------------- threefry2x32 (JAX partitionable — verified) ----------------
__device__ __forceinline__ void threefry2x32(unsigned k0, unsigned k1, unsigned x0, unsigned x1,
                                             unsigned &o0, unsigned &o1){
  unsigned ks0=k0, ks1=k1, ks2=k0^k1^0x1BD11BDAu;
  x0 += ks0; x1 += ks1;
#define RND(r) { x0 += x1; x1 = rotl32(x1, r); x1 ^= x0; }
  RND(13u) RND(15u) RND(26u) RND(6u)   x0+=ks1; x1+=ks2+1u;
  RND(17u) RND(29u) RND(16u) RND(24u)  x0+=ks2; x1+=ks0+2u;
  RND(13u) RND(15u) RND(26u) RND(6u)   x0+=ks0; x1+=ks1+3u;
  RND(17u) RND(29u) RND(16u) RND(24u)  x0+=ks1; x1+=ks2+4u;
  RND(13u) RND(15u) RND(26u) RND(6u)   x0+=ks2; x1+=ks0+5u;
#undef RND
  o0=x0; o1=x1;
}

// ---------------- prep: 12 weight transposes + bias-cat + threefry idx ----------------
__global__ __launch_bounds__(256) void k_prep(
    const float* __restrict__ Wq, const float* __restrict__ Wk,
    const float* __restrict__ Wv, const float* __restrict__ Wo,
    const float* __restrict__ f1W, const float* __restrict__ f2W,
    const float* __restrict__ bq, const float* __restrict__ bk, const float* __restrict__ bv,
    ushort* __restrict__ wt, float* __restrict__ bcat, int* __restrict__ sidx)
{
  const size_t F1T=1048576, F2T=2097152, LSTR=3145728;
  int bid = blockIdx.x, t = threadIdx.x;
  if (bid >= 6145){
    int i = (bid-6145)*256 + t;
    const int total = L_SEQ*NSAMP;
    if (i < total){
      unsigned o0, o1;
      threefry2x32(0u, 42u, 0u, (unsigned)(total + i), o0, o1);
      sidx[i] = (int)((o0 ^ o1) & (unsigned)(L_SEQ-1));
    }
    return;
  }
  if (bid == 6144){
    for (int i=t; i<2*1536; i+=256){
      int l = i / 1536, r = i - l*1536;
      float v = (r<512) ? bq[l*DM+r] : (r<1024) ? bk[l*DM+r-512] : bv[l*DM+r-1024];
      bcat[i] = v;
    }
    return;
  }
  int l = bid >= 3072; bid -= l*3072;
  const float* src; ushort* dst; int K, N, tile;
  if (bid < 1024){
    int m = bid >> 8; tile = bid & 255;
    src = (m==0?Wq:m==1?Wk:m==2?Wv:Wo) + (size_t)l*DM*DM;
    dst = wt + (size_t)l*LSTR + (size_t)m*262144; K=DM; N=DM;
  } else if (bid < 2048){
    tile = bid-1024; src = f1W + (size_t)l*DM*DFF; dst = wt + (size_t)l*LSTR + F1T; K=DM; N=DFF;
  } else {
    tile = bid-2048; src = f2W + (size_t)l*DFF*DM; dst = wt + (size_t)l*LSTR + F2T; K=DFF; N=DM;
  }
  int ntn = N/32;
  int n0 = (tile % ntn)*32, k0 = (tile / ntn)*32;
  __shared__ float tl[32][33];
  int r = t >> 5, c = t & 31;
  for (int rr=r; rr<32; rr+=8) tl[rr][c] = src[(size_t)(k0+rr)*N + n0 + c];
  __syncthreads();
  for (int rr=r; rr<32; rr+=8)
    dst[(size_t)(n0+rr)*K + k0 + c] = f2bf(tl[c][rr]);
}

// ---------------- embedding (writes f32 x and bf16 xb) ----------------
__global__ __launch_bounds__(256) void k_embed(const int* __restrict__ tok,
    const float* __restrict__ x_enc, const float* __restrict__ x_mark,
    const float* __restrict__ embW, const float* __restrict__ convW,
    const float* __restrict__ timeW, const float* __restrict__ timeb,
    float* __restrict__ x, ushort* __restrict__ xb){
  int bl = blockIdx.x; int b = bl >> 11; int l = bl & (L_SEQ-1);
  __shared__ float xin[21];
  __shared__ float xm[4];
  int t = threadIdx.x;
  if (t < 21){
    int tt = t/7, i = t - tt*7;
    int ll = (l + tt - 1) & (L_SEQ-1);
    xin[t] = x_enc[((size_t)b*L_SEQ + ll)*7 + i];
  }
  if (t >= 32 && t < 36) xm[t-32] = x_mark[((size_t)b*L_SEQ + l)*4 + (t-32)];
  __syncthreads();
  int tk = tok[bl];
  #pragma unroll
  for (int rep=0; rep<2; rep++){
    int d = t + rep*256;
    float v = embW[(size_t)tk*DM + d];
    const float* w = convW + (size_t)d*21;
    float cv = 0.f;
    #pragma unroll
    for (int tt=0; tt<3; tt++)
      #pragma unroll
      for (int i=0; i<7; i++)
        cv = fmaf(xin[tt*7+i], w[i*3+tt], cv);
    v += cv;
    float tv = timeb[d];
    #pragma unroll
    for (int m=0; m<4; m++) tv = fmaf(xm[m], timeW[m*DM + d], tv);
    v += tv;
    int j = d >> 1;
    float div = expf((float)(2*j) * (-0.017988946039015984f));
    float ang = (float)l * div;
    v += (d & 1) ? cosf(ang) : sinf(ang);
    x[(size_t)bl*DM + d] = v;
    xb[(size_t)bl*DM + d] = f2bf(v);
  }
}

// ---------------- bf16 MFMA GEMM, 64x64 tile, BK=64, 4 waves (2x2) x 32x32 ----------------
// (proven shape: rounds 5-7) + bijective XCD-aware block swizzle for L2 locality
enum { MG_ADD=0, MG_GELU_BF16=1, MG_QKV=2 };

__global__ __launch_bounds__(256) void k_mgemm(
    const ushort* __restrict__ A, const ushort* __restrict__ Bt,
    const float* __restrict__ bias, float* __restrict__ Cf,
    ushort* __restrict__ Cb, int M, int N, int K, int mode)
{
  __shared__ ushort As[64][64];
  __shared__ ushort Bs[64][64];
  int tid = threadIdx.x, lane = tid & 63, wid = tid >> 6;
  // XCD swizzle: all grids here have nwg % 8 == 0; contiguous sid-chunks land on one XCD
  int nwg = gridDim.x*gridDim.y;
  int id  = blockIdx.y*gridDim.x + blockIdx.x;
  int sid = (id & 7)*(nwg >> 3) + (id >> 3);
  int bx = sid % gridDim.x, by = sid / gridDim.x;
  int m0 = by*64, n0 = bx*64;
  int wr = wid >> 1, wc = wid & 1;
  f32x4 acc[2][2];
  #pragma unroll
  for (int i=0;i<2;i++)
    #pragma unroll
    for(int j=0;j<2;j++) acc[i][j] = (f32x4){0.f,0.f,0.f,0.f};

  for (int k0 = 0; k0 < K; k0 += 64){
    __syncthreads();
    #pragma unroll
    for (int it=0; it<2; it++){
      int e   = it*256 + tid;
      int row = e >> 3, seg = e & 7;
      __builtin_amdgcn_global_load_lds(
        (const __attribute__((address_space(1))) void*)(A + (size_t)(m0+row)*K + k0 + seg*8),
        (__attribute__((address_space(3))) void*)(&As[0][0] + (size_t)e*8), 16, 0, 0);
      __builtin_amdgcn_global_load_lds(
        (const __attribute__((address_space(1))) void*)(Bt + (size_t)(n0+row)*K + k0 + seg*8),
        (__attribute__((address_space(3))) void*)(&Bs[0][0] + (size_t)e*8), 16, 0, 0);
    }
    __syncthreads();
    #pragma unroll
    for (int kk=0; kk<2; kk++){
      bf16x8 af[2], bfv[2];
      int ko = kk*32 + (lane>>4)*8;
      #pragma unroll
      for (int i=0;i<2;i++) af[i]  = *(const bf16x8*)&As[wr*32 + i*16 + (lane&15)][ko];
      #pragma unroll
      for (int j=0;j<2;j++) bfv[j] = *(const bf16x8*)&Bs[wc*32 + j*16 + (lane&15)][ko];
      #pragma unroll
      for (int i=0;i<2;i++)
        #pragma unroll
        for (int j=0;j<2;j++)
          acc[i][j] = __builtin_amdgcn_mfma_f32_16x16x32_bf16(af[i], bfv[j], acc[i][j], 0,0,0);
    }
  }

  int fq = lane >> 4, fr = lane & 15;
  for (int i=0;i<2;i++){
    for (int j=0;j<2;j++){
      #pragma unroll
      for (int jj=0;jj<4;jj++){
        int r = m0 + wr*32 + i*16 + fq*4 + jj;
        int c = n0 + wc*32 + j*16 + fr;
        float v = acc[i][j][jj] + bias[c];
        if (mode == MG_ADD){
          Cf[(size_t)r*N + c] += v;
        } else if (mode == MG_GELU_BF16){
          float g = 0.5f*v*(1.f + erff(v*0.70710678118654752f));
          Cb[(size_t)r*N + c] = f2bf(g);
        } else {
          int b = r >> 11, l = r & (L_SEQ-1), m3 = c >> 9, hh = (c>>6)&7, d = c & 63;
          Cb[(size_t)m3*4194304 + (((size_t)b*NH + hh)*L_SEQ + l)*64 + d] = f2bf(v);
        }
      }
    }
  }
}

// ---------------- V mean: 2-stage ----------------
__global__ __launch_bounds__(256) void k_vmean1(const ushort* __restrict__ V, float* __restrict__ part){
  int blk = blockIdx.x;
  int bh = blk >> 5, ch = blk & 31;
  int t = threadIdx.x, d = t & 63, c = t >> 6;
  const ushort* Vb = V + (size_t)bh*L_SEQ*DK + (size_t)(ch*64 + c*16)*DK;
  float s = 0.f;
  #pragma unroll
  for (int r=0; r<16; r++) s += bf2f(Vb[r*DK + d]);
  __shared__ float red[256];
  red[t]=s; __syncthreads();
  if (t < 64) part[(size_t)blk*64 + t] = red[t]+red[t+64]+red[t+128]+red[t+192];
}
__global__ __launch_bounds__(64) void k_vmean2(const float* __restrict__ part, float* __restrict__ vmean){
  int bh = blockIdx.x, d = threadIdx.x;
  float s = 0.f;
  #pragma unroll
  for (int ch=0; ch<32; ch++) s += part[(size_t)(bh*32+ch)*64 + d];
  vmean[bh*64+d] = s * (1.f/(float)L_SEQ);
}

// ---------------- M-score: full-wave sample/dim decomposition ----------------
__global__ __launch_bounds__(256) void k_mscore(const ushort* __restrict__ Q, const ushort* __restrict__ Km,
    const int* __restrict__ idx, float* __restrict__ M){
  int wid = threadIdx.x >> 6, lane = threadIdx.x & 63;
  int g = blockIdx.x*4 + wid;          // bh*L + l
  int l = g & (L_SEQ-1), bh = g >> 11;
  int sg = lane >> 3, dg = lane & 7;

  bf16x8 qv = *(const bf16x8*)(Q + (size_t)g*64 + dg*8);
  float qf[8];
  #pragma unroll
  for (int e=0;e<8;e++) qf[e] = bf2f((ushort)qv[e]);

  const int* ir = idx + l*NSAMP;
  int ki[5];
  #pragma unroll
  for (int i=0;i<5;i++) ki[i] = ir[i*8 + sg];
  const ushort* Kb = Km + (size_t)bh*L_SEQ*64;
  bf16x8 kv[5];
  #pragma unroll
  for (int i=0;i<5;i++) kv[i] = *(const bf16x8*)(Kb + (size_t)ki[i]*64 + dg*8);

  float mx = -INFINITY, sm = 0.f;
  #pragma unroll
  for (int i=0;i<5;i++){
    float d = 0.f;
    #pragma unroll
    for (int e=0;e<8;e++) d = fmaf(qf[e], bf2f((ushort)kv[i][e]), d);
    #pragma unroll
    for (int off=1; off<8; off<<=1) d += __shfl_xor(d, off);
    mx = fmaxf(mx, d);
    sm += d;
  }
  #pragma unroll
  for (int off=1; off<64; off<<=1){
    mx = fmaxf(mx, __shfl_xor(mx, off));
    sm += __shfl_xor(sm, off);
  }
  if (lane==0) M[g] = mx - sm * (1.f/(8.f*(float)NSAMP));
}

// ---------------- top-40 per (b,h): single wave, register-resident ----------------
__global__ __launch_bounds__(64) void k_topk(const float* __restrict__ M, int* __restrict__ Mtop){
  int bh = blockIdx.x, lane = threadIdx.x;
  float v[32];
  #pragma unroll
  for (int s=0; s<32; s++) v[s] = M[(size_t)bh*L_SEQ + s*64 + lane];
  for (int sel=0; sel<NSAMP; sel++){
    float best = -INFINITY; int bs = 0;
    #pragma unroll
    for (int s=0; s<32; s++){
      if (v[s] > best){ best = v[s]; bs = s; }
    }
    int bidx = bs*64 + lane;
    #pragma unroll
    for (int off=1; off<64; off<<=1){
      float ov = __shfl_xor(best, off);
      int   oi = __shfl_xor(bidx, off);
      if (ov > best || (ov == best && oi < bidx)){ best = ov; bidx = oi; }
    }
    if (lane == 0) Mtop[bh*NSAMP + sel] = bidx;
    int cs = bidx >> 6, cl = bidx & 63;
    if (lane == cl){
      #pragma unroll
      for (int s=0; s<32; s++) if (s == cs) v[s] = -INFINITY;
    }
  }
}

// ---------------- ctx init = broadcast mean V ----------------
__global__ __launch_bounds__(256) void k_ctxfill(const float* __restrict__ vmean, ushort* __restrict__ ctx){
  int i = blockIdx.x*256 + threadIdx.x;
  int c = i & (DM-1);
  int b = i >> 20;
  int h = c >> 6, d = c & 63;
  ctx[i] = f2bf(vmean[((b<<3)+h)*64 + d]);
}

// ---------------- MFMA flash attention, stage 1: per-chunk partials ----------------
__global__ __launch_bounds__(256) void k_attn1(const ushort* __restrict__ Q, const ushort* __restrict__ K,
    const ushort* __restrict__ V, const int* __restrict__ Mtop,
    float* __restrict__ pm, float* __restrict__ ps, float* __restrict__ pO){
  int bid = blockIdx.x;
  int xcd = bid & 7, idx = bid >> 3;
  int bh = xcd*4 + (idx & 3), ch = idx >> 2;
  int l0 = ch * CKEY;
  int t = threadIdx.x, lane = t & 63, w = t >> 6;

  __shared__ ushort Qs[48][64];
  __shared__ ushort Ks[CKEY][64];
  __shared__ ushort Vs[CKEY][66];
  __shared__ ushort Ps[48][136];
  __shared__ float rmax[4][48];
  __shared__ float rsum[4][48];
  __shared__ float Oacc[48][64];
  __shared__ int qidx[48];

  if (t < 40) qidx[t] = Mtop[bh*NSAMP + t];
  const ushort* Kb = K + ((size_t)bh*L_SEQ + l0)*64;
  #pragma unroll
  for (int i=0;i<4;i++){
    int e = i*256 + t;
    __builtin_amdgcn_global_load_lds(
      (const __attribute__((address_space(1))) void*)(Kb + (size_t)e*8),
      (__attribute__((address_space(3))) void*)(&Ks[0][0] + (size_t)e*8), 16, 0, 0);
  }
  __syncthreads();

  const ushort* Qb = Q + (size_t)bh*L_SEQ*64;
  {
    int row = t >> 3, seg = t & 7;
    bf16x8 qv = *(const bf16x8*)(Qb + (size_t)qidx[row]*64 + seg*8);
    *(bf16x8*)&Qs[row][seg*8] = qv;
    if (t < 128){
      int r2 = 32 + (t>>3);
      bf16x8 z = (bf16x8){0,0,0,0,0,0,0,0};
      if (r2 < 40) z = *(const bf16x8*)(Qb + (size_t)qidx[r2]*64 + (t&7)*8);
      *(bf16x8*)&Qs[r2][(t&7)*8] = z;
    }
  }
  const ushort* Vb = V + ((size_t)bh*L_SEQ + l0)*64;
  #pragma unroll
  for (int i=0;i<4;i++){
    int e = i*256 + t;
    int row = e >> 3, seg = e & 7;
    bf16x8 vv = *(const bf16x8*)(Vb + (size_t)e*8);
    *(bf16x8*)&Vs[row][seg*8] = vv;
  }
  __syncthreads();

  for (int i=t; i<48*64; i+=256) ((float*)Oacc)[i] = 0.f;

  f32x4 sa[3][2];
  #pragma unroll
  for (int i=0;i<3;i++) for (int j=0;j<2;j++) sa[i][j] = (f32x4){0.f,0.f,0.f,0.f};
  #pragma unroll
  for (int ks=0; ks<2; ks++){
    int ko = ks*32 + (lane>>4)*8;
    bf16x8 af[3], bf[2];
    #pragma unroll
    for (int i=0;i<3;i++) af[i] = *(const bf16x8*)&Qs[i*16 + (lane&15)][ko];
    #pragma unroll
    for (int j=0;j<2;j++) bf[j] = *(const bf16x8*)&Ks[w*32 + j*16 + (lane&15)][ko];
    #pragma unroll
    for (int i=0;i<3;i++)
      #pragma unroll
      for (int j=0;j<2;j++)
        sa[i][j] = __builtin_amdgcn_mfma_f32_16x16x32_bf16(af[i], bf[j], sa[i][j], 0,0,0);
  }
  #pragma unroll
  for (int i=0;i<3;i++)
    #pragma unroll
    for (int j=0;j<2;j++)
      #pragma unroll
      for (int jj=0;jj<4;jj++) sa[i][j][jj] *= 0.125f;
  #pragma unroll
  for (int i=0;i<3;i++){
    #pragma unroll
    for (int jj=0;jj<4;jj++){
      float mx = fmaxf(sa[i][0][jj], sa[i][1][jj]);
      #pragma unroll
      for (int off=1; off<16; off<<=1) mx = fmaxf(mx, __shfl_xor(mx, off));
      if ((lane&15)==0) rmax[w][i*16 + (lane>>4)*4 + jj] = mx;
    }
  }
  __syncthreads();
  #pragma unroll
  for (int i=0;i<3;i++){
    #pragma unroll
    for (int jj=0;jj<4;jj++){
      int row = i*16 + (lane>>4)*4 + jj;
      float m = fmaxf(fmaxf(rmax[0][row], rmax[1][row]), fmaxf(rmax[2][row], rmax[3][row]));
      float p0 = __expf(sa[i][0][jj] - m);
      float p1 = __expf(sa[i][1][jj] - m);
      Ps[row][w*32 + (lane&15)]      = f2bf(p0);
      Ps[row][w*32 + 16 + (lane&15)] = f2bf(p1);
      float sm = p0 + p1;
      #pragma unroll
      for (int off=1; off<16; off<<=1) sm += __shfl_xor(sm, off);
      if ((lane&15)==0) rsum[w][row] = sm;
    }
  }
  __syncthreads();

  f32x4 oa[3][4];
  #pragma unroll
  for (int i=0;i<3;i++) for (int j=0;j<4;j++) oa[i][j] = (f32x4){0.f,0.f,0.f,0.f};
  {
    bf16x8 pa[3], vb[4];
    int kbase = w*32 + (lane>>4)*8;
    #pragma unroll
    for (int i=0;i<3;i++) pa[i] = *(const bf16x8*)&Ps[i*16 + (lane&15)][kbase];
    #pragma unroll
    for (int j=0;j<4;j++){
      #pragma unroll
      for (int e=0;e<8;e++) vb[j][e] = (short)Vs[kbase + e][j*16 + (lane&15)];
    }
    #pragma unroll
    for (int i=0;i<3;i++)
      #pragma unroll
      for (int j=0;j<4;j++)
        oa[i][j] = __builtin_amdgcn_mfma_f32_16x16x32_bf16(pa[i], vb[j], oa[i][j], 0,0,0);
  }
  #pragma unroll
  for (int ww=0; ww<4; ww++){
    if (w == ww){
      #pragma unroll
      for (int i=0;i<3;i++)
        #pragma unroll
        for (int j=0;j<4;j++)
          #pragma unroll
          for (int jj=0;jj<4;jj++)
            Oacc[i*16 + (lane>>4)*4 + jj][j*16 + (lane&15)] += oa[i][j][jj];
    }
    __syncthreads();
  }

  size_t base = ((size_t)bh*PARTC + ch);
  if (t < 40){
    float m = fmaxf(fmaxf(rmax[0][t], rmax[1][t]), fmaxf(rmax[2][t], rmax[3][t]));
    pm[base*40 + t] = m;
    ps[base*40 + t] = rsum[0][t]+rsum[1][t]+rsum[2][t]+rsum[3][t];
  }
  {
    int row = t >> 3, d0 = (t&7)*8;
    float* dst = pO + (base*48 + row)*64 + d0;
    #pragma unroll
    for (int e=0;e<8;e++) dst[e] = Oacc[row][d0+e];
    if (t < 64){
      int r2 = 32 + (t>>3);
      float* dst2 = pO + (base*48 + r2)*64 + d0;
      #pragma unroll
      for (int e=0;e<8;e++) dst2[e] = Oacc[r2][d0+e];
    }
  }
}

// ---------------- flash attention, stage 2: combine chunks, scatter to ctx ----------------
__global__ __launch_bounds__(256) void k_attn2(const float* __restrict__ pm, const float* __restrict__ ps,
    const float* __restrict__ pO, const int* __restrict__ Mtop, ushort* __restrict__ ctx){
  int bh = blockIdx.x, b = bh >> 3, h = bh & 7;
  int t = threadIdx.x;
  __shared__ float wch[PARTC][40];
  __shared__ float inv_s[40];
  __shared__ int qidx[40];
  if (t < 40){
    qidx[t] = Mtop[bh*NSAMP + t];
    float m = -INFINITY;
    #pragma unroll
    for (int c=0;c<PARTC;c++) m = fmaxf(m, pm[((size_t)bh*PARTC + c)*40 + t]);
    float s = 0.f;
    #pragma unroll
    for (int c=0;c<PARTC;c++){
      float wc = __expf(pm[((size_t)bh*PARTC + c)*40 + t] - m);
      wch[c][t] = wc;
      s += wc * ps[((size_t)bh*PARTC + c)*40 + t];
    }
    inv_s[t] = 1.f / s;
  }
  __syncthreads();
  #pragma unroll
  for (int iter=0; iter<2; iter++){
    int row = iter*32 + (t>>3);
    if (row < 40){
      int d0 = (t&7)*8;
      float o[8] = {0.f,0.f,0.f,0.f,0.f,0.f,0.f,0.f};
      for (int c=0;c<PARTC;c++){
        const float* pp = pO + (((size_t)bh*PARTC + c)*48 + row)*64 + d0;
        float wc = wch[c][row];
        float4 a = *(const float4*)pp, b4 = *(const float4*)(pp+4);
        o[0]=fmaf(wc,a.x,o[0]); o[1]=fmaf(wc,a.y,o[1]); o[2]=fmaf(wc,a.z,o[2]); o[3]=fmaf(wc,a.w,o[3]);
        o[4]=fmaf(wc,b4.x,o[4]); o[5]=fmaf(wc,b4.y,o[5]); o[6]=fmaf(wc,b4.z,o[6]); o[7]=fmaf(wc,b4.w,o[7]);
      }
      float is = inv_s[row];
      bf16x8 wv;
      #pragma unroll
      for (int e=0;e<8;e++) wv[e] = (short)f2bf(o[e]*is);
      *(bf16x8*)(ctx + ((size_t)b*L_SEQ + qidx[row])*DM + h*64 + d0) = wv;
    }
  }
}

// ---------------- LayerNorm: one wave per row ----------------
__global__ __launch_bounds__(256) void k_ln(float* __restrict__ x,
    const float* __restrict__ g, const float* __restrict__ b,
    ushort* __restrict__ xb){
  int row = blockIdx.x*4 + (threadIdx.x>>6);
  int lane = threadIdx.x & 63;
  float* xr = x + (size_t)row*DM + lane*8;
  float4 v0 = *(const float4*)(xr);
  float4 v1 = *(const float4*)(xr + 4);
  float s = v0.x+v0.y+v0.z+v0.w+v1.x+v1.y+v1.z+v1.w;
  #pragma unroll
  for (int off=1; off<64; off<<=1) s += __shfl_xor(s, off);
  float mu = s * (1.f/(float)DM);
  float d0=v0.x-mu, d1=v0.y-mu, d2=v0.z-mu, d3=v0.w-mu;
  float d4=v1.x-mu, d5=v1.y-mu, d6=v1.z-mu, d7=v1.w-mu;
  float q = d0*d0+d1*d1+d2*d2+d3*d3+d4*d4+d5*d5+d6*d6+d7*d7;
  #pragma unroll
  for (int off=1; off<64; off<<=1) q += __shfl_xor(q, off);
  float r = rsqrtf(q * (1.f/(float)DM) + 1e-5f);
  float4 g0 = *(const float4*)(g + lane*8);
  float4 g1 = *(const float4*)(g + lane*8 + 4);
  float4 b0 = *(const float4*)(b + lane*8);
  float4 b1 = *(const float4*)(b + lane*8 + 4);
  float o0=d0*r*g0.x+b0.x, o1=d1*r*g0.y+b0.y, o2=d2*r*g0.z+b0.z, o3=d3*r*g0.w+b0.w;
  float o4=d4*r*g1.x+b1.x, o5=d5*r*g1.y+b1.y, o6=d6*r*g1.z+b1.z, o7=d7*r*g1.w+b1.w;
  *(float4*)(xr)     = (float4){o0,o1,o2,o3};
  *(float4*)(xr + 4) = (float4){o4,o5,o6,o7};
  if (xb){
    bf16x8 w;
    w[0]=(short)f2bf(o0); w[1]=(short)f2bf(o1); w[2]=(short)f2bf(o2); w[3]=(short)f2bf(o3);
    w[4]=(short)f2bf(o4); w[5]=(short)f2bf(o5); w[6]=(short)f2bf(o6); w[7]=(short)f2bf(o7);
    *(bf16x8*)(xb + (size_t)row*DM + lane*8) = w;
  }
}

// ---------------- final logits ----------------
__global__ __launch_bounds__(64) void k_logits(const float* __restrict__ x, const float* __restrict__ embW,
                                               float* __restrict__ out){
  int bid = blockIdx.x;
  int b = bid / NGRID, g = bid - b*NGRID;
  const float* xr = x + ((size_t)b*L_SEQ + (L_SEQ-1))*DM;
  const float* er = embW + (size_t)g*DM;
  int lane = threadIdx.x;
  float s = 0.f;
  for (int d=lane; d<DM; d+=64) s = fmaf(xr[d], er[d], s);
  for (int off=32; off; off>>=1) s += __shfl_xor(s, off);
  if (lane==0) out[bid] = s;
}

extern "C" void kernel_launch(void* const* d_in, const int* in_sizes, int n_in,
                              void* d_out, int out_size, void* d_ws, size_t ws_size,
                              hipStream_t stream) {
  const int*   tok    = (const int*)d_in[0];
  const float* x_enc  = (const float*)d_in[1];
  const float* x_mark = (const float*)d_in[2];
  const float* embW   = (const float*)d_in[3];
  const float* convW  = (const float*)d_in[4];
  const float* timeW  = (const float*)d_in[5];
  const float* timeb  = (const float*)d_in[6];
  const float* Wq = (const float*)d_in[7];  const float* bq = (const float*)d_in[8];
  const float* Wk = (const float*)d_in[9];  const float* bk = (const float*)d_in[10];
  const float* Wv = (const float*)d_in[11]; const float* bv = (const float*)d_in[12];
  const float* Wo = (const float*)d_in[13]; const float* bo = (const float*)d_in[14];
  const float* ln1g = (const float*)d_in[15]; const float* ln1b = (const float*)d_in[16];
  const float* ln2g = (const float*)d_in[17]; const float* ln2b = (const float*)d_in[18];
  const float* f1W = (const float*)d_in[19]; const float* f1b = (const float*)d_in[20];
  const float* f2W = (const float*)d_in[21]; const float* f2b = (const float*)d_in[22];
  const float* nrmg = (const float*)d_in[23]; const float* nrmb = (const float*)d_in[24];
  float* out = (float*)d_out;

  char* ws = (char*)d_ws;
  float*  x    = (float*) (ws);                       // 16 MB f32 residual
  ushort* xb   = (ushort*)(ws + ((size_t)16<<20));    //  8 MB bf16 GEMM input
  ushort* q    = (ushort*)(ws + ((size_t)24<<20));    //  8 MB (B,H,L,64); k,v follow
  ushort* kbuf = (ushort*)(ws + ((size_t)32<<20));
  ushort* vbuf = (ushort*)(ws + ((size_t)40<<20));
  ushort* ctx  = (ushort*)(ws + ((size_t)48<<20));    //  8 MB
  ushort* hbuf = (ushort*)(ws + ((size_t)24<<20));    // 32 MB, overlays q/k/v/ctx
  ushort* wt   = (ushort*)(ws + ((size_t)56<<20));    // 12 MB bf16 weights^T
  float*  Mbuf = (float*) (ws + ((size_t)69<<20));
  int*    Mtop = (int*)   (ws + ((size_t)70<<20));
  int*    sidx = (int*)   (ws + ((size_t)71<<20));
  float*  vmean= (float*) (ws + ((size_t)72<<20));
  float*  bcat = (float*) (ws + ((size_t)73<<20));
  float*  part = (float*) (ws + ((size_t)74<<20));
  float*  pO   = (float*) (ws + ((size_t)75<<20));    // 6.3 MB
  float*  pmb  = (float*) (ws + ((size_t)82<<20));
  float*  psb  = (float*) (ws + ((size_t)82<<20) + 102400);

  const int Mrows = NB*L_SEQ;   // 8192
  const size_t WQT=0, WOT=786432, F1T=1048576, F2T=2097152, LSTR=3145728;

  k_prep<<<6465, 256, 0, stream>>>(Wq, Wk, Wv, Wo, f1W, f2W, bq, bk, bv, wt, bcat, sidx);
  k_embed<<<NB*L_SEQ, 256, 0, stream>>>(tok, x_enc, x_mark, embW, convW, timeW, timeb, x, xb);

  for (int l=0; l<2; l++){
    size_t b5 = (size_t)l*DM;
    ushort* wl = wt + (size_t)l*LSTR;

    k_mgemm<<<dim3(1536/64, Mrows/64), 256, 0, stream>>>(xb, wl+WQT, bcat+l*1536, nullptr, q, Mrows, 1536, DM, MG_QKV);
    k_vmean1<<<NB*NH*32, 256, 0, stream>>>(vbuf, part);
    k_vmean2<<<NB*NH, 64, 0, stream>>>(part, vmean);
    k_mscore<<<NB*NH*L_SEQ/4, 256, 0, stream>>>(q, kbuf, sidx, Mbuf);
    k_topk<<<NB*NH, 64, 0, stream>>>(Mbuf, Mtop);
    k_ctxfill<<<(NB*L_SEQ*DM)/256, 256, 0, stream>>>(vmean, ctx);
    k_attn1<<<NB*NH*PARTC, 256, 0, stream>>>(q, kbuf, vbuf, Mtop, pmb, psb, pO);
    k_attn2<<<NB*NH, 256, 0, stream>>>(pmb, psb, pO, Mtop, ctx);
    k_mgemm<<<dim3(DM/64, Mrows/64), 256, 0, stream>>>(ctx, wl+WOT, bo+b5, x, nullptr, Mrows, DM, DM, MG_ADD);
    k_ln<<<Mrows/4, 256, 0, stream>>>(x, ln1g+b5, ln1b+b5, xb);
    k_mgemm<<<dim3(DFF/64, Mrows/64), 256, 0, stream>>>(xb, wl+F1T, f1b + (size_t)l*DFF, nullptr, hbuf, Mrows, DFF, DM, MG_GELU_BF16);
    k_mgemm<<<dim3(DM/64, Mrows/64), 256, 0, stream>>>(hbuf, wl+F2T, f2b+b5, x, nullptr, Mrows, DM, DFF, MG_ADD);
    k_ln<<<Mrows/4, 256, 0, stream>>>(x, ln2g+b5, ln2b+b5, xb);
  }
  k_ln<<<Mrows/4, 256, 0, stream>>>(x, nrmg, nrmb, nullptr);
  k_logits<<<NB*NGRID, 64, 0, stream>>>(x, embW, out);
}

// Round 10
// 518.663 us; speedup vs baseline: 2.0198x; 1.0583x over previous
//
#include <hip/hip_runtime.h>
#include <hip/hip_bf16.h>

#define L_SEQ 2048
#define NB    4
#define DM    512
#define NH    8
#define DK    64
#define DFF   2048
#define NSAMP 40
#define NGRID 100
#define PARTC 16      // key chunks per (b,h)
#define CKEY  128     // keys per chunk

typedef __attribute__((ext_vector_type(8))) short bf16x8;
typedef __attribute__((ext_vector_type(4))) float f32x4;

__device__ __forceinline__ unsigned rotl32(unsigned x, unsigned r){ return (x<<r)|(x>>(32u-r)); }
__device__ __forceinline__ float bf2f(ushort u){ return __uint_as_float(((unsigned)u)<<16); }
__device__ __forceinline__ ushort f2bf(float f){
  unsigned u = __float_as_uint(f);
  unsigned r = (u + 0x7fffu + ((u>>16)&1u)) >> 16;
  return (ushort)r;
}

// ---------------- threefry2x32 (JAX partitionable — verified) ----------------
__device__ __forceinline__ void threefry2x32(unsigned k0, unsigned k1, unsigned x0, unsigned x1,
                                             unsigned &o0, unsigned &o1){
  unsigned ks0=k0, ks1=k1, ks2=k0^k1^0x1BD11BDAu;
  x0 += ks0; x1 += ks1;
#define RND(r) { x0 += x1; x1 = rotl32(x1, r); x1 ^= x0; }
  RND(13u) RND(15u) RND(26u) RND(6u)   x0+=ks1; x1+=ks2+1u;
  RND(17u) RND(29u) RND(16u) RND(24u)  x0+=ks2; x1+=ks0+2u;
  RND(13u) RND(15u) RND(26u) RND(6u)   x0+=ks0; x1+=ks1+3u;
  RND(17u) RND(29u) RND(16u) RND(24u)  x0+=ks1; x1+=ks2+4u;
  RND(13u) RND(15u) RND(26u) RND(6u)   x0+=ks2; x1+=ks0+5u;
#undef RND
  o0=x0; o1=x1;
}

// ---------------- prep: 12 weight transposes + bias-cat + threefry idx ----------------
__global__ __launch_bounds__(256) void k_prep(
    const float* __restrict__ Wq, const float* __restrict__ Wk,
    const float* __restrict__ Wv, const float* __restrict__ Wo,
    const float* __restrict__ f1W, const float* __restrict__ f2W,
    const float* __restrict__ bq, const float* __restrict__ bk, const float* __restrict__ bv,
    ushort* __restrict__ wt, float* __restrict__ bcat, int* __restrict__ sidx)
{
  const size_t F1T=1048576, F2T=2097152, LSTR=3145728;
  int bid = blockIdx.x, t = threadIdx.x;
  if (bid >= 6145){
    int i = (bid-6145)*256 + t;
    const int total = L_SEQ*NSAMP;
    if (i < total){
      unsigned o0, o1;
      threefry2x32(0u, 42u, 0u, (unsigned)(total + i), o0, o1);
      sidx[i] = (int)((o0 ^ o1) & (unsigned)(L_SEQ-1));
    }
    return;
  }
  if (bid == 6144){
    for (int i=t; i<2*1536; i+=256){
      int l = i / 1536, r = i - l*1536;
      float v = (r<512) ? bq[l*DM+r] : (r<1024) ? bk[l*DM+r-512] : bv[l*DM+r-1024];
      bcat[i] = v;
    }
    return;
  }
  int l = bid >= 3072; bid -= l*3072;
  const float* src; ushort* dst; int K, N, tile;
  if (bid < 1024){
    int m = bid >> 8; tile = bid & 255;
    src = (m==0?Wq:m==1?Wk:m==2?Wv:Wo) + (size_t)l*DM*DM;
    dst = wt + (size_t)l*LSTR + (size_t)m*262144; K=DM; N=DM;
  } else if (bid < 2048){
    tile = bid-1024; src = f1W + (size_t)l*DM*DFF; dst = wt + (size_t)l*LSTR + F1T; K=DM; N=DFF;
  } else {
    tile = bid-2048; src = f2W + (size_t)l*DFF*DM; dst = wt + (size_t)l*LSTR + F2T; K=DFF; N=DM;
  }
  int ntn = N/32;
  int n0 = (tile % ntn)*32, k0 = (tile / ntn)*32;
  __shared__ float tl[32][33];
  int r = t >> 5, c = t & 31;
  for (int rr=r; rr<32; rr+=8) tl[rr][c] = src[(size_t)(k0+rr)*N + n0 + c];
  __syncthreads();
  for (int rr=r; rr<32; rr+=8)
    dst[(size_t)(n0+rr)*K + k0 + c] = f2bf(tl[c][rr]);
}

// ---------------- embedding (writes f32 x and bf16 xb) ----------------
__global__ __launch_bounds__(256) void k_embed(const int* __restrict__ tok,
    const float* __restrict__ x_enc, const float* __restrict__ x_mark,
    const float* __restrict__ embW, const float* __restrict__ convW,
    const float* __restrict__ timeW, const float* __restrict__ timeb,
    float* __restrict__ x, ushort* __restrict__ xb){
  int bl = blockIdx.x; int b = bl >> 11; int l = bl & (L_SEQ-1);
  __shared__ float xin[21];
  __shared__ float xm[4];
  int t = threadIdx.x;
  if (t < 21){
    int tt = t/7, i = t - tt*7;
    int ll = (l + tt - 1) & (L_SEQ-1);
    xin[t] = x_enc[((size_t)b*L_SEQ + ll)*7 + i];
  }
  if (t >= 32 && t < 36) xm[t-32] = x_mark[((size_t)b*L_SEQ + l)*4 + (t-32)];
  __syncthreads();
  int tk = tok[bl];
  #pragma unroll
  for (int rep=0; rep<2; rep++){
    int d = t + rep*256;
    float v = embW[(size_t)tk*DM + d];
    const float* w = convW + (size_t)d*21;
    float cv = 0.f;
    #pragma unroll
    for (int tt=0; tt<3; tt++)
      #pragma unroll
      for (int i=0; i<7; i++)
        cv = fmaf(xin[tt*7+i], w[i*3+tt], cv);
    v += cv;
    float tv = timeb[d];
    #pragma unroll
    for (int m=0; m<4; m++) tv = fmaf(xm[m], timeW[m*DM + d], tv);
    v += tv;
    int j = d >> 1;
    float div = expf((float)(2*j) * (-0.017988946039015984f));
    float ang = (float)l * div;
    v += (d & 1) ? cosf(ang) : sinf(ang);
    x[(size_t)bl*DM + d] = v;
    xb[(size_t)bl*DM + d] = f2bf(v);
  }
}

// ---------------- bf16 MFMA GEMM, 64x64 tile + T2 XOR-swizzled LDS ----------------
// Swizzle (rule #21): linear LDS dest; global SOURCE segment pre-swizzled
// (gseg = seg ^ (row&7)); ds_read applies the same involution.
enum { MG_ADD=0, MG_GELU_BF16=1, MG_QKV=2 };

__global__ __launch_bounds__(256) void k_mgemm(
    const ushort* __restrict__ A, const ushort* __restrict__ Bt,
    const float* __restrict__ bias, float* __restrict__ Cf,
    ushort* __restrict__ Cb, int M, int N, int K, int mode)
{
  __shared__ ushort As[64][64];
  __shared__ ushort Bs[64][64];
  int tid = threadIdx.x, lane = tid & 63, wid = tid >> 6;
  // XCD swizzle (bijective: all grids here have nwg % 8 == 0)
  int nwg = gridDim.x*gridDim.y;
  int id  = blockIdx.y*gridDim.x + blockIdx.x;
  int sid = (id & 7)*(nwg >> 3) + (id >> 3);
  int bx = sid % gridDim.x, by = sid / gridDim.x;
  int m0 = by*64, n0 = bx*64;
  int wr = wid >> 1, wc = wid & 1;
  f32x4 acc[2][2];
  #pragma unroll
  for (int i=0;i<2;i++)
    #pragma unroll
    for(int j=0;j<2;j++) acc[i][j] = (f32x4){0.f,0.f,0.f,0.f};

  for (int k0 = 0; k0 < K; k0 += 64){
    __syncthreads();
    #pragma unroll
    for (int it=0; it<2; it++){
      int e   = it*256 + tid;
      int row = e >> 3, seg = e & 7;
      int gseg = seg ^ (row & 7);            // pre-swizzled source segment
      __builtin_amdgcn_global_load_lds(
        (const __attribute__((address_space(1))) void*)(A + (size_t)(m0+row)*K + k0 + gseg*8),
        (__attribute__((address_space(3))) void*)(&As[0][0] + (size_t)e*8), 16, 0, 0);
      __builtin_amdgcn_global_load_lds(
        (const __attribute__((address_space(1))) void*)(Bt + (size_t)(n0+row)*K + k0 + gseg*8),
        (__attribute__((address_space(3))) void*)(&Bs[0][0] + (size_t)e*8), 16, 0, 0);
    }
    __syncthreads();
    #pragma unroll
    for (int kk=0; kk<2; kk++){
      bf16x8 af[2], bfv[2];
      int seg = kk*4 + (lane>>4);            // global K segment wanted
      #pragma unroll
      for (int i=0;i<2;i++){
        int row = wr*32 + i*16 + (lane&15);
        af[i]  = *(const bf16x8*)&As[row][(seg ^ (row&7))*8];
      }
      #pragma unroll
      for (int j=0;j<2;j++){
        int row = wc*32 + j*16 + (lane&15);
        bfv[j] = *(const bf16x8*)&Bs[row][(seg ^ (row&7))*8];
      }
      #pragma unroll
      for (int i=0;i<2;i++)
        #pragma unroll
        for (int j=0;j<2;j++)
          acc[i][j] = __builtin_amdgcn_mfma_f32_16x16x32_bf16(af[i], bfv[j], acc[i][j], 0,0,0);
    }
  }

  int fq = lane >> 4, fr = lane & 15;
  for (int i=0;i<2;i++){
    for (int j=0;j<2;j++){
      #pragma unroll
      for (int jj=0;jj<4;jj++){
        int r = m0 + wr*32 + i*16 + fq*4 + jj;
        int c = n0 + wc*32 + j*16 + fr;
        float v = acc[i][j][jj] + bias[c];
        if (mode == MG_ADD){
          Cf[(size_t)r*N + c] += v;
        } else if (mode == MG_GELU_BF16){
          float g = 0.5f*v*(1.f + erff(v*0.70710678118654752f));
          Cb[(size_t)r*N + c] = f2bf(g);
        } else {
          int b = r >> 11, l = r & (L_SEQ-1), m3 = c >> 9, hh = (c>>6)&7, d = c & 63;
          Cb[(size_t)m3*4194304 + (((size_t)b*NH + hh)*L_SEQ + l)*64 + d] = f2bf(v);
        }
      }
    }
  }
}

// ---------------- V mean: 2-stage ----------------
__global__ __launch_bounds__(256) void k_vmean1(const ushort* __restrict__ V, float* __restrict__ part){
  int blk = blockIdx.x;
  int bh = blk >> 5, ch = blk & 31;
  int t = threadIdx.x, d = t & 63, c = t >> 6;
  const ushort* Vb = V + (size_t)bh*L_SEQ*DK + (size_t)(ch*64 + c*16)*DK;
  float s = 0.f;
  #pragma unroll
  for (int r=0; r<16; r++) s += bf2f(Vb[r*DK + d]);
  __shared__ float red[256];
  red[t]=s; __syncthreads();
  if (t < 64) part[(size_t)blk*64 + t] = red[t]+red[t+64]+red[t+128]+red[t+192];
}
__global__ __launch_bounds__(64) void k_vmean2(const float* __restrict__ part, float* __restrict__ vmean){
  int bh = blockIdx.x, d = threadIdx.x;
  float s = 0.f;
  #pragma unroll
  for (int ch=0; ch<32; ch++) s += part[(size_t)(bh*32+ch)*64 + d];
  vmean[bh*64+d] = s * (1.f/(float)L_SEQ);
}

// ---------------- M-score: full-wave sample/dim decomposition ----------------
__global__ __launch_bounds__(256) void k_mscore(const ushort* __restrict__ Q, const ushort* __restrict__ Km,
    const int* __restrict__ idx, float* __restrict__ M){
  int wid = threadIdx.x >> 6, lane = threadIdx.x & 63;
  int g = blockIdx.x*4 + wid;          // bh*L + l
  int l = g & (L_SEQ-1), bh = g >> 11;
  int sg = lane >> 3, dg = lane & 7;

  bf16x8 qv = *(const bf16x8*)(Q + (size_t)g*64 + dg*8);
  float qf[8];
  #pragma unroll
  for (int e=0;e<8;e++) qf[e] = bf2f((ushort)qv[e]);

  const int* ir = idx + l*NSAMP;
  int ki[5];
  #pragma unroll
  for (int i=0;i<5;i++) ki[i] = ir[i*8 + sg];
  const ushort* Kb = Km + (size_t)bh*L_SEQ*64;
  bf16x8 kv[5];
  #pragma unroll
  for (int i=0;i<5;i++) kv[i] = *(const bf16x8*)(Kb + (size_t)ki[i]*64 + dg*8);

  float mx = -INFINITY, sm = 0.f;
  #pragma unroll
  for (int i=0;i<5;i++){
    float d = 0.f;
    #pragma unroll
    for (int e=0;e<8;e++) d = fmaf(qf[e], bf2f((ushort)kv[i][e]), d);
    #pragma unroll
    for (int off=1; off<8; off<<=1) d += __shfl_xor(d, off);
    mx = fmaxf(mx, d);
    sm += d;
  }
  #pragma unroll
  for (int off=1; off<64; off<<=1){
    mx = fmaxf(mx, __shfl_xor(mx, off));
    sm += __shfl_xor(sm, off);
  }
  if (lane==0) M[g] = mx - sm * (1.f/(8.f*(float)NSAMP));
}

// ---------------- top-40 per (b,h): single wave, register-resident ----------------
__global__ __launch_bounds__(64) void k_topk(const float* __restrict__ M, int* __restrict__ Mtop){
  int bh = blockIdx.x, lane = threadIdx.x;
  float v[32];
  #pragma unroll
  for (int s=0; s<32; s++) v[s] = M[(size_t)bh*L_SEQ + s*64 + lane];
  for (int sel=0; sel<NSAMP; sel++){
    float best = -INFINITY; int bs = 0;
    #pragma unroll
    for (int s=0; s<32; s++){
      if (v[s] > best){ best = v[s]; bs = s; }
    }
    int bidx = bs*64 + lane;
    #pragma unroll
    for (int off=1; off<64; off<<=1){
      float ov = __shfl_xor(best, off);
      int   oi = __shfl_xor(bidx, off);
      if (ov > best || (ov == best && oi < bidx)){ best = ov; bidx = oi; }
    }
    if (lane == 0) Mtop[bh*NSAMP + sel] = bidx;
    int cs = bidx >> 6, cl = bidx & 63;
    if (lane == cl){
      #pragma unroll
      for (int s=0; s<32; s++) if (s == cs) v[s] = -INFINITY;
    }
  }
}

// ---------------- ctx init = broadcast mean V ----------------
__global__ __launch_bounds__(256) void k_ctxfill(const float* __restrict__ vmean, ushort* __restrict__ ctx){
  int i = blockIdx.x*256 + threadIdx.x;
  int c = i & (DM-1);
  int b = i >> 20;
  int h = c >> 6, d = c & 63;
  ctx[i] = f2bf(vmean[((b<<3)+h)*64 + d]);
}

// ---------------- MFMA flash attention, stage 1: per-chunk partials ----------------
__global__ __launch_bounds__(256) void k_attn1(const ushort* __restrict__ Q, const ushort* __restrict__ K,
    const ushort* __restrict__ V, const int* __restrict__ Mtop,
    float* __restrict__ pm, float* __restrict__ ps, float* __restrict__ pO){
  int bid = blockIdx.x;
  int xcd = bid & 7, idx = bid >> 3;
  int bh = xcd*4 + (idx & 3), ch = idx >> 2;
  int l0 = ch * CKEY;
  int t = threadIdx.x, lane = t & 63, w = t >> 6;

  __shared__ ushort Qs[48][64];
  __shared__ ushort Ks[CKEY][64];
  __shared__ ushort Vs[CKEY][66];
  __shared__ ushort Ps[48][136];
  __shared__ float rmax[4][48];
  __shared__ float rsum[4][48];
  __shared__ float Oacc[48][64];
  __shared__ int qidx[48];

  if (t < 40) qidx[t] = Mtop[bh*NSAMP + t];
  const ushort* Kb = K + ((size_t)bh*L_SEQ + l0)*64;
  #pragma unroll
  for (int i=0;i<4;i++){
    int e = i*256 + t;
    __builtin_amdgcn_global_load_lds(
      (const __attribute__((address_space(1))) void*)(Kb + (size_t)e*8),
      (__attribute__((address_space(3))) void*)(&Ks[0][0] + (size_t)e*8), 16, 0, 0);
  }
  __syncthreads();

  const ushort* Qb = Q + (size_t)bh*L_SEQ*64;
  {
    int row = t >> 3, seg = t & 7;
    bf16x8 qv = *(const bf16x8*)(Qb + (size_t)qidx[row]*64 + seg*8);
    *(bf16x8*)&Qs[row][seg*8] = qv;
    if (t < 128){
      int r2 = 32 + (t>>3);
      bf16x8 z = (bf16x8){0,0,0,0,0,0,0,0};
      if (r2 < 40) z = *(const bf16x8*)(Qb + (size_t)qidx[r2]*64 + (t&7)*8);
      *(bf16x8*)&Qs[r2][(t&7)*8] = z;
    }
  }
  const ushort* Vb = V + ((size_t)bh*L_SEQ + l0)*64;
  #pragma unroll
  for (int i=0;i<4;i++){
    int e = i*256 + t;
    int row = e >> 3, seg = e & 7;
    bf16x8 vv = *(const bf16x8*)(Vb + (size_t)e*8);
    *(bf16x8*)&Vs[row][seg*8] = vv;
  }
  __syncthreads();

  for (int i=t; i<48*64; i+=256) ((float*)Oacc)[i] = 0.f;

  f32x4 sa[3][2];
  #pragma unroll
  for (int i=0;i<3;i++) for (int j=0;j<2;j++) sa[i][j] = (f32x4){0.f,0.f,0.f,0.f};
  #pragma unroll
  for (int ks=0; ks<2; ks++){
    int ko = ks*32 + (lane>>4)*8;
    bf16x8 af[3], bf[2];
    #pragma unroll
    for (int i=0;i<3;i++) af[i] = *(const bf16x8*)&Qs[i*16 + (lane&15)][ko];
    #pragma unroll
    for (int j=0;j<2;j++) bf[j] = *(const bf16x8*)&Ks[w*32 + j*16 + (lane&15)][ko];
    #pragma unroll
    for (int i=0;i<3;i++)
      #pragma unroll
      for (int j=0;j<2;j++)
        sa[i][j] = __builtin_amdgcn_mfma_f32_16x16x32_bf16(af[i], bf[j], sa[i][j], 0,0,0);
  }
  #pragma unroll
  for (int i=0;i<3;i++)
    #pragma unroll
    for (int j=0;j<2;j++)
      #pragma unroll
      for (int jj=0;jj<4;jj++) sa[i][j][jj] *= 0.125f;
  #pragma unroll
  for (int i=0;i<3;i++){
    #pragma unroll
    for (int jj=0;jj<4;jj++){
      float mx = fmaxf(sa[i][0][jj], sa[i][1][jj]);
      #pragma unroll
      for (int off=1; off<16; off<<=1) mx = fmaxf(mx, __shfl_xor(mx, off));
      if ((lane&15)==0) rmax[w][i*16 + (lane>>4)*4 + jj] = mx;
    }
  }
  __syncthreads();
  #pragma unroll
  for (int i=0;i<3;i++){
    #pragma unroll
    for (int jj=0;jj<4;jj++){
      int row = i*16 + (lane>>4)*4 + jj;
      float m = fmaxf(fmaxf(rmax[0][row], rmax[1][row]), fmaxf(rmax[2][row], rmax[3][row]));
      float p0 = __expf(sa[i][0][jj] - m);
      float p1 = __expf(sa[i][1][jj] - m);
      Ps[row][w*32 + (lane&15)]      = f2bf(p0);
      Ps[row][w*32 + 16 + (lane&15)] = f2bf(p1);
      float sm = p0 + p1;
      #pragma unroll
      for (int off=1; off<16; off<<=1) sm += __shfl_xor(sm, off);
      if ((lane&15)==0) rsum[w][row] = sm;
    }
  }
  __syncthreads();

  f32x4 oa[3][4];
  #pragma unroll
  for (int i=0;i<3;i++) for (int j=0;j<4;j++) oa[i][j] = (f32x4){0.f,0.f,0.f,0.f};
  {
    bf16x8 pa[3], vb[4];
    int kbase = w*32 + (lane>>4)*8;
    #pragma unroll
    for (int i=0;i<3;i++) pa[i] = *(const bf16x8*)&Ps[i*16 + (lane&15)][kbase];
    #pragma unroll
    for (int j=0;j<4;j++){
      #pragma unroll
      for (int e=0;e<8;e++) vb[j][e] = (short)Vs[kbase + e][j*16 + (lane&15)];
    }
    #pragma unroll
    for (int i=0;i<3;i++)
      #pragma unroll
      for (int j=0;j<4;j++)
        oa[i][j] = __builtin_amdgcn_mfma_f32_16x16x32_bf16(pa[i], vb[j], oa[i][j], 0,0,0);
  }
  #pragma unroll
  for (int ww=0; ww<4; ww++){
    if (w == ww){
      #pragma unroll
      for (int i=0;i<3;i++)
        #pragma unroll
        for (int j=0;j<4;j++)
          #pragma unroll
          for (int jj=0;jj<4;jj++)
            Oacc[i*16 + (lane>>4)*4 + jj][j*16 + (lane&15)] += oa[i][j][jj];
    }
    __syncthreads();
  }

  size_t base = ((size_t)bh*PARTC + ch);
  if (t < 40){
    float m = fmaxf(fmaxf(rmax[0][t], rmax[1][t]), fmaxf(rmax[2][t], rmax[3][t]));
    pm[base*40 + t] = m;
    ps[base*40 + t] = rsum[0][t]+rsum[1][t]+rsum[2][t]+rsum[3][t];
  }
  {
    int row = t >> 3, d0 = (t&7)*8;
    float* dst = pO + (base*48 + row)*64 + d0;
    #pragma unroll
    for (int e=0;e<8;e++) dst[e] = Oacc[row][d0+e];
    if (t < 64){
      int r2 = 32 + (t>>3);
      float* dst2 = pO + (base*48 + r2)*64 + d0;
      #pragma unroll
      for (int e=0;e<8;e++) dst2[e] = Oacc[r2][d0+e];
    }
  }
}

// ---------------- flash attention, stage 2: combine chunks, scatter to ctx ----------------
__global__ __launch_bounds__(256) void k_attn2(const float* __restrict__ pm, const float* __restrict__ ps,
    const float* __restrict__ pO, const int* __restrict__ Mtop, ushort* __restrict__ ctx){
  int bh = blockIdx.x, b = bh >> 3, h = bh & 7;
  int t = threadIdx.x;
  __shared__ float wch[PARTC][40];
  __shared__ float inv_s[40];
  __shared__ int qidx[40];
  if (t < 40){
    qidx[t] = Mtop[bh*NSAMP + t];
    float m = -INFINITY;
    #pragma unroll
    for (int c=0;c<PARTC;c++) m = fmaxf(m, pm[((size_t)bh*PARTC + c)*40 + t]);
    float s = 0.f;
    #pragma unroll
    for (int c=0;c<PARTC;c++){
      float wc = __expf(pm[((size_t)bh*PARTC + c)*40 + t] - m);
      wch[c][t] = wc;
      s += wc * ps[((size_t)bh*PARTC + c)*40 + t];
    }
    inv_s[t] = 1.f / s;
  }
  __syncthreads();
  #pragma unroll
  for (int iter=0; iter<2; iter++){
    int row = iter*32 + (t>>3);
    if (row < 40){
      int d0 = (t&7)*8;
      float o[8] = {0.f,0.f,0.f,0.f,0.f,0.f,0.f,0.f};
      for (int c=0;c<PARTC;c++){
        const float* pp = pO + (((size_t)bh*PARTC + c)*48 + row)*64 + d0;
        float wc = wch[c][row];
        float4 a = *(const float4*)pp, b4 = *(const float4*)(pp+4);
        o[0]=fmaf(wc,a.x,o[0]); o[1]=fmaf(wc,a.y,o[1]); o[2]=fmaf(wc,a.z,o[2]); o[3]=fmaf(wc,a.w,o[3]);
        o[4]=fmaf(wc,b4.x,o[4]); o[5]=fmaf(wc,b4.y,o[5]); o[6]=fmaf(wc,b4.z,o[6]); o[7]=fmaf(wc,b4.w,o[7]);
      }
      float is = inv_s[row];
      bf16x8 wv;
      #pragma unroll
      for (int e=0;e<8;e++) wv[e] = (short)f2bf(o[e]*is);
      *(bf16x8*)(ctx + ((size_t)b*L_SEQ + qidx[row])*DM + h*64 + d0) = wv;
    }
  }
}

// ---------------- LayerNorm: one wave per row ----------------
__global__ __launch_bounds__(256) void k_ln(float* __restrict__ x,
    const float* __restrict__ g, const float* __restrict__ b,
    ushort* __restrict__ xb){
  int row = blockIdx.x*4 + (threadIdx.x>>6);
  int lane = threadIdx.x & 63;
  float* xr = x + (size_t)row*DM + lane*8;
  float4 v0 = *(const float4*)(xr);
  float4 v1 = *(const float4*)(xr + 4);
  float s = v0.x+v0.y+v0.z+v0.w+v1.x+v1.y+v1.z+v1.w;
  #pragma unroll
  for (int off=1; off<64; off<<=1) s += __shfl_xor(s, off);
  float mu = s * (1.f/(float)DM);
  float d0=v0.x-mu, d1=v0.y-mu, d2=v0.z-mu, d3=v0.w-mu;
  float d4=v1.x-mu, d5=v1.y-mu, d6=v1.z-mu, d7=v1.w-mu;
  float q = d0*d0+d1*d1+d2*d2+d3*d3+d4*d4+d5*d5+d6*d6+d7*d7;
  #pragma unroll
  for (int off=1; off<64; off<<=1) q += __shfl_xor(q, off);
  float r = rsqrtf(q * (1.f/(float)DM) + 1e-5f);
  float4 g0 = *(const float4*)(g + lane*8);
  float4 g1 = *(const float4*)(g + lane*8 + 4);
  float4 b0 = *(const float4*)(b + lane*8);
  float4 b1 = *(const float4*)(b + lane*8 + 4);
  float o0=d0*r*g0.x+b0.x, o1=d1*r*g0.y+b0.y, o2=d2*r*g0.z+b0.z, o3=d3*r*g0.w+b0.w;
  float o4=d4*r*g1.x+b1.x, o5=d5*r*g1.y+b1.y, o6=d6*r*g1.z+b1.z, o7=d7*r*g1.w+b1.w;
  *(float4*)(xr)     = (float4){o0,o1,o2,o3};
  *(float4*)(xr + 4) = (float4){o4,o5,o6,o7};
  if (xb){
    bf16x8 w;
    w[0]=(short)f2bf(o0); w[1]=(short)f2bf(o1); w[2]=(short)f2bf(o2); w[3]=(short)f2bf(o3);
    w[4]=(short)f2bf(o4); w[5]=(short)f2bf(o5); w[6]=(short)f2bf(o6); w[7]=(short)f2bf(o7);
    *(bf16x8*)(xb + (size_t)row*DM + lane*8) = w;
  }
}

// ---------------- final logits ----------------
__global__ __launch_bounds__(64) void k_logits(const float* __restrict__ x, const float* __restrict__ embW,
                                               float* __restrict__ out){
  int bid = blockIdx.x;
  int b = bid / NGRID, g = bid - b*NGRID;
  const float* xr = x + ((size_t)b*L_SEQ + (L_SEQ-1))*DM;
  const float* er = embW + (size_t)g*DM;
  int lane = threadIdx.x;
  float s = 0.f;
  for (int d=lane; d<DM; d+=64) s = fmaf(xr[d], er[d], s);
  for (int off=32; off; off>>=1) s += __shfl_xor(s, off);
  if (lane==0) out[bid] = s;
}

extern "C" void kernel_launch(void* const* d_in, const int* in_sizes, int n_in,
                              void* d_out, int out_size, void* d_ws, size_t ws_size,
                              hipStream_t stream) {
  const int*   tok    = (const int*)d_in[0];
  const float* x_enc  = (const float*)d_in[1];
  const float* x_mark = (const float*)d_in[2];
  const float* embW   = (const float*)d_in[3];
  const float* convW  = (const float*)d_in[4];
  const float* timeW  = (const float*)d_in[5];
  const float* timeb  = (const float*)d_in[6];
  const float* Wq = (const float*)d_in[7];  const float* bq = (const float*)d_in[8];
  const float* Wk = (const float*)d_in[9];  const float* bk = (const float*)d_in[10];
  const float* Wv = (const float*)d_in[11]; const float* bv = (const float*)d_in[12];
  const float* Wo = (const float*)d_in[13]; const float* bo = (const float*)d_in[14];
  const float* ln1g = (const float*)d_in[15]; const float* ln1b = (const float*)d_in[16];
  const float* ln2g = (const float*)d_in[17]; const float* ln2b = (const float*)d_in[18];
  const float* f1W = (const float*)d_in[19]; const float* f1b = (const float*)d_in[20];
  const float* f2W = (const float*)d_in[21]; const float* f2b = (const float*)d_in[22];
  const float* nrmg = (const float*)d_in[23]; const float* nrmb = (const float*)d_in[24];
  float* out = (float*)d_out;

  char* ws = (char*)d_ws;
  float*  x    = (float*) (ws);                       // 16 MB f32 residual
  ushort* xb   = (ushort*)(ws + ((size_t)16<<20));    //  8 MB bf16 GEMM input
  ushort* q    = (ushort*)(ws + ((size_t)24<<20));    //  8 MB (B,H,L,64); k,v follow
  ushort* kbuf = (ushort*)(ws + ((size_t)32<<20));
  ushort* vbuf = (ushort*)(ws + ((size_t)40<<20));
  ushort* ctx  = (ushort*)(ws + ((size_t)48<<20));    //  8 MB
  ushort* hbuf = (ushort*)(ws + ((size_t)24<<20));    // 32 MB, overlays q/k/v/ctx
  ushort* wt   = (ushort*)(ws + ((size_t)56<<20));    // 12 MB bf16 weights^T
  float*  Mbuf = (float*) (ws + ((size_t)69<<20));
  int*    Mtop = (int*)   (ws + ((size_t)70<<20));
  int*    sidx = (int*)   (ws + ((size_t)71<<20));
  float*  vmean= (float*) (ws + ((size_t)72<<20));
  float*  bcat = (float*) (ws + ((size_t)73<<20));
  float*  part = (float*) (ws + ((size_t)74<<20));
  float*  pO   = (float*) (ws + ((size_t)75<<20));    // 6.3 MB
  float*  pmb  = (float*) (ws + ((size_t)82<<20));
  float*  psb  = (float*) (ws + ((size_t)82<<20) + 102400);

  const int Mrows = NB*L_SEQ;   // 8192
  const size_t WQT=0, WOT=786432, F1T=1048576, F2T=2097152, LSTR=3145728;

  k_prep<<<6465, 256, 0, stream>>>(Wq, Wk, Wv, Wo, f1W, f2W, bq, bk, bv, wt, bcat, sidx);
  k_embed<<<NB*L_SEQ, 256, 0, stream>>>(tok, x_enc, x_mark, embW, convW, timeW, timeb, x, xb);

  for (int l=0; l<2; l++){
    size_t b5 = (size_t)l*DM;
    ushort* wl = wt + (size_t)l*LSTR;

    k_mgemm<<<dim3(1536/64, Mrows/64), 256, 0, stream>>>(xb, wl+WQT, bcat+l*1536, nullptr, q, Mrows, 1536, DM, MG_QKV);
    k_vmean1<<<NB*NH*32, 256, 0, stream>>>(vbuf, part);
    k_vmean2<<<NB*NH, 64, 0, stream>>>(part, vmean);
    k_mscore<<<NB*NH*L_SEQ/4, 256, 0, stream>>>(q, kbuf, sidx, Mbuf);
    k_topk<<<NB*NH, 64, 0, stream>>>(Mbuf, Mtop);
    k_ctxfill<<<(NB*L_SEQ*DM)/256, 256, 0, stream>>>(vmean, ctx);
    k_attn1<<<NB*NH*PARTC, 256, 0, stream>>>(q, kbuf, vbuf, Mtop, pmb, psb, pO);
    k_attn2<<<NB*NH, 256, 0, stream>>>(pmb, psb, pO, Mtop, ctx);
    k_mgemm<<<dim3(DM/64, Mrows/64), 256, 0, stream>>>(ctx, wl+WOT, bo+b5, x, nullptr, Mrows, DM, DM, MG_ADD);
    k_ln<<<Mrows/4, 256, 0, stream>>>(x, ln1g+b5, ln1b+b5, xb);
    k_mgemm<<<dim3(DFF/64, Mrows/64), 256, 0, stream>>>(xb, wl+F1T, f1b + (size_t)l*DFF, nullptr, hbuf, Mrows, DFF, DM, MG_GELU_BF16);
    k_mgemm<<<dim3(DM/64, Mrows/64), 256, 0, stream>>>(hbuf, wl+F2T, f2b+b5, x, nullptr, Mrows, DM, DFF, MG_ADD);
    k_ln<<<Mrows/4, 256, 0, stream>>>(x, ln2g+b5, ln2b+b5, xb);
  }
  k_ln<<<Mrows/4, 256, 0, stream>>>(x, nrmg, nrmb, nullptr);
  k_logits<<<NB*NGRID, 64, 0, stream>>>(x, embW, out);
}

// Round 11
// 494.734 us; speedup vs baseline: 2.1175x; 1.0484x over previous
//
#include <hip/hip_runtime.h>
#include <hip/hip_bf16.h>

#define L_SEQ 2048
#define NB    4
#define DM    512
#define NH    8
#define DK    64
#define DFF   2048
#define NSAMP 40
#define NGRID 100
#define PARTC 16      // key chunks per (b,h)
#define CKEY  128     // keys per chunk

typedef __attribute__((ext_vector_type(8))) short bf16x8;
typedef __attribute__((ext_vector_type(4))) float f32x4;

__device__ __forceinline__ unsigned rotl32(unsigned x, unsigned r){ return (x<<r)|(x>>(32u-r)); }
__device__ __forceinline__ float bf2f(ushort u){ return __uint_as_float(((unsigned)u)<<16); }
__device__ __forceinline__ ushort f2bf(float f){
  unsigned u = __float_as_uint(f);
  unsigned r = (u + 0x7fffu + ((u>>16)&1u)) >> 16;
  return (ushort)r;
}
// monotone float -> uint map (larger uint == larger float)
__device__ __forceinline__ unsigned fkey(float f){
  unsigned u = __float_as_uint(f);
  return (u & 0x80000000u) ? ~u : (u | 0x80000000u);
}

// ---------------- threefry2x32 (JAX partitionable — verified) ----------------
__device__ __forceinline__ void threefry2x32(unsigned k0, unsigned k1, unsigned x0, unsigned x1,
                                             unsigned &o0, unsigned &o1){
  unsigned ks0=k0, ks1=k1, ks2=k0^k1^0x1BD11BDAu;
  x0 += ks0; x1 += ks1;
#define RND(r) { x0 += x1; x1 = rotl32(x1, r); x1 ^= x0; }
  RND(13u) RND(15u) RND(26u) RND(6u)   x0+=ks1; x1+=ks2+1u;
  RND(17u) RND(29u) RND(16u) RND(24u)  x0+=ks2; x1+=ks0+2u;
  RND(13u) RND(15u) RND(26u) RND(6u)   x0+=ks0; x1+=ks1+3u;
  RND(17u) RND(29u) RND(16u) RND(24u)  x0+=ks1; x1+=ks2+4u;
  RND(13u) RND(15u) RND(26u) RND(6u)   x0+=ks2; x1+=ks0+5u;
#undef RND
  o0=x0; o1=x1;
}

// ---------------- prep: 12 weight transposes + bias-cat + threefry idx ----------------
__global__ __launch_bounds__(256) void k_prep(
    const float* __restrict__ Wq, const float* __restrict__ Wk,
    const float* __restrict__ Wv, const float* __restrict__ Wo,
    const float* __restrict__ f1W, const float* __restrict__ f2W,
    const float* __restrict__ bq, const float* __restrict__ bk, const float* __restrict__ bv,
    ushort* __restrict__ wt, float* __restrict__ bcat, int* __restrict__ sidx)
{
  const size_t F1T=1048576, F2T=2097152, LSTR=3145728;
  int bid = blockIdx.x, t = threadIdx.x;
  if (bid >= 6145){
    int i = (bid-6145)*256 + t;
    const int total = L_SEQ*NSAMP;
    if (i < total){
      unsigned o0, o1;
      threefry2x32(0u, 42u, 0u, (unsigned)(total + i), o0, o1);
      sidx[i] = (int)((o0 ^ o1) & (unsigned)(L_SEQ-1));
    }
    return;
  }
  if (bid == 6144){
    for (int i=t; i<2*1536; i+=256){
      int l = i / 1536, r = i - l*1536;
      float v = (r<512) ? bq[l*DM+r] : (r<1024) ? bk[l*DM+r-512] : bv[l*DM+r-1024];
      bcat[i] = v;
    }
    return;
  }
  int l = bid >= 3072; bid -= l*3072;
  const float* src; ushort* dst; int K, N, tile;
  if (bid < 1024){
    int m = bid >> 8; tile = bid & 255;
    src = (m==0?Wq:m==1?Wk:m==2?Wv:Wo) + (size_t)l*DM*DM;
    dst = wt + (size_t)l*LSTR + (size_t)m*262144; K=DM; N=DM;
  } else if (bid < 2048){
    tile = bid-1024; src = f1W + (size_t)l*DM*DFF; dst = wt + (size_t)l*LSTR + F1T; K=DM; N=DFF;
  } else {
    tile = bid-2048; src = f2W + (size_t)l*DFF*DM; dst = wt + (size_t)l*LSTR + F2T; K=DFF; N=DM;
  }
  int ntn = N/32;
  int n0 = (tile % ntn)*32, k0 = (tile / ntn)*32;
  __shared__ float tl[32][33];
  int r = t >> 5, c = t & 31;
  for (int rr=r; rr<32; rr+=8) tl[rr][c] = src[(size_t)(k0+rr)*N + n0 + c];
  __syncthreads();
  for (int rr=r; rr<32; rr+=8)
    dst[(size_t)(n0+rr)*K + k0 + c] = f2bf(tl[c][rr]);
}

// ---------------- embedding (writes f32 x and bf16 xb) ----------------
__global__ __launch_bounds__(256) void k_embed(const int* __restrict__ tok,
    const float* __restrict__ x_enc, const float* __restrict__ x_mark,
    const float* __restrict__ embW, const float* __restrict__ convW,
    const float* __restrict__ timeW, const float* __restrict__ timeb,
    float* __restrict__ x, ushort* __restrict__ xb){
  int bl = blockIdx.x; int b = bl >> 11; int l = bl & (L_SEQ-1);
  __shared__ float xin[21];
  __shared__ float xm[4];
  int t = threadIdx.x;
  if (t < 21){
    int tt = t/7, i = t - tt*7;
    int ll = (l + tt - 1) & (L_SEQ-1);
    xin[t] = x_enc[((size_t)b*L_SEQ + ll)*7 + i];
  }
  if (t >= 32 && t < 36) xm[t-32] = x_mark[((size_t)b*L_SEQ + l)*4 + (t-32)];
  __syncthreads();
  int tk = tok[bl];
  #pragma unroll
  for (int rep=0; rep<2; rep++){
    int d = t + rep*256;
    float v = embW[(size_t)tk*DM + d];
    const float* w = convW + (size_t)d*21;
    float cv = 0.f;
    #pragma unroll
    for (int tt=0; tt<3; tt++)
      #pragma unroll
      for (int i=0; i<7; i++)
        cv = fmaf(xin[tt*7+i], w[i*3+tt], cv);
    v += cv;
    float tv = timeb[d];
    #pragma unroll
    for (int m=0; m<4; m++) tv = fmaf(xm[m], timeW[m*DM + d], tv);
    v += tv;
    int j = d >> 1;
    float div = expf((float)(2*j) * (-0.017988946039015984f));
    float ang = (float)l * div;
    v += (d & 1) ? cosf(ang) : sinf(ang);
    x[(size_t)bl*DM + d] = v;
    xb[(size_t)bl*DM + d] = f2bf(v);
  }
}

// ---------------- bf16 MFMA GEMM, 64x64 tile + T2 XOR-swizzled LDS ----------------
enum { MG_ADD=0, MG_GELU_BF16=1, MG_QKV=2 };

__global__ __launch_bounds__(256) void k_mgemm(
    const ushort* __restrict__ A, const ushort* __restrict__ Bt,
    const float* __restrict__ bias, float* __restrict__ Cf,
    ushort* __restrict__ Cb, int M, int N, int K, int mode)
{
  __shared__ ushort As[64][64];
  __shared__ ushort Bs[64][64];
  int tid = threadIdx.x, lane = tid & 63, wid = tid >> 6;
  int nwg = gridDim.x*gridDim.y;
  int id  = blockIdx.y*gridDim.x + blockIdx.x;
  int sid = (id & 7)*(nwg >> 3) + (id >> 3);
  int bx = sid % gridDim.x, by = sid / gridDim.x;
  int m0 = by*64, n0 = bx*64;
  int wr = wid >> 1, wc = wid & 1;
  f32x4 acc[2][2];
  #pragma unroll
  for (int i=0;i<2;i++)
    #pragma unroll
    for(int j=0;j<2;j++) acc[i][j] = (f32x4){0.f,0.f,0.f,0.f};

  for (int k0 = 0; k0 < K; k0 += 64){
    __syncthreads();
    #pragma unroll
    for (int it=0; it<2; it++){
      int e   = it*256 + tid;
      int row = e >> 3, seg = e & 7;
      int gseg = seg ^ (row & 7);            // pre-swizzled source segment
      __builtin_amdgcn_global_load_lds(
        (const __attribute__((address_space(1))) void*)(A + (size_t)(m0+row)*K + k0 + gseg*8),
        (__attribute__((address_space(3))) void*)(&As[0][0] + (size_t)e*8), 16, 0, 0);
      __builtin_amdgcn_global_load_lds(
        (const __attribute__((address_space(1))) void*)(Bt + (size_t)(n0+row)*K + k0 + gseg*8),
        (__attribute__((address_space(3))) void*)(&Bs[0][0] + (size_t)e*8), 16, 0, 0);
    }
    __syncthreads();
    #pragma unroll
    for (int kk=0; kk<2; kk++){
      bf16x8 af[2], bfv[2];
      int seg = kk*4 + (lane>>4);
      #pragma unroll
      for (int i=0;i<2;i++){
        int row = wr*32 + i*16 + (lane&15);
        af[i]  = *(const bf16x8*)&As[row][(seg ^ (row&7))*8];
      }
      #pragma unroll
      for (int j=0;j<2;j++){
        int row = wc*32 + j*16 + (lane&15);
        bfv[j] = *(const bf16x8*)&Bs[row][(seg ^ (row&7))*8];
      }
      #pragma unroll
      for (int i=0;i<2;i++)
        #pragma unroll
        for (int j=0;j<2;j++)
          acc[i][j] = __builtin_amdgcn_mfma_f32_16x16x32_bf16(af[i], bfv[j], acc[i][j], 0,0,0);
    }
  }

  int fq = lane >> 4, fr = lane & 15;
  for (int i=0;i<2;i++){
    for (int j=0;j<2;j++){
      #pragma unroll
      for (int jj=0;jj<4;jj++){
        int r = m0 + wr*32 + i*16 + fq*4 + jj;
        int c = n0 + wc*32 + j*16 + fr;
        float v = acc[i][j][jj] + bias[c];
        if (mode == MG_ADD){
          Cf[(size_t)r*N + c] += v;
        } else if (mode == MG_GELU_BF16){
          float g = 0.5f*v*(1.f + erff(v*0.70710678118654752f));
          Cb[(size_t)r*N + c] = f2bf(g);
        } else {
          int b = r >> 11, l = r & (L_SEQ-1), m3 = c >> 9, hh = (c>>6)&7, d = c & 63;
          Cb[(size_t)m3*4194304 + (((size_t)b*NH + hh)*L_SEQ + l)*64 + d] = f2bf(v);
        }
      }
    }
  }
}

// ---------------- V mean: 2-stage ----------------
__global__ __launch_bounds__(256) void k_vmean1(const ushort* __restrict__ V, float* __restrict__ part){
  int blk = blockIdx.x;
  int bh = blk >> 5, ch = blk & 31;
  int t = threadIdx.x, d = t & 63, c = t >> 6;
  const ushort* Vb = V + (size_t)bh*L_SEQ*DK + (size_t)(ch*64 + c*16)*DK;
  float s = 0.f;
  #pragma unroll
  for (int r=0; r<16; r++) s += bf2f(Vb[r*DK + d]);
  __shared__ float red[256];
  red[t]=s; __syncthreads();
  if (t < 64) part[(size_t)blk*64 + t] = red[t]+red[t+64]+red[t+128]+red[t+192];
}
__global__ __launch_bounds__(64) void k_vmean2(const float* __restrict__ part, float* __restrict__ vmean){
  int bh = blockIdx.x, d = threadIdx.x;
  float s = 0.f;
  #pragma unroll
  for (int ch=0; ch<32; ch++) s += part[(size_t)(bh*32+ch)*64 + d];
  vmean[bh*64+d] = s * (1.f/(float)L_SEQ);
}

// ---------------- M-score: full-wave sample/dim decomposition ----------------
__global__ __launch_bounds__(256) void k_mscore(const ushort* __restrict__ Q, const ushort* __restrict__ Km,
    const int* __restrict__ idx, float* __restrict__ M){
  int wid = threadIdx.x >> 6, lane = threadIdx.x & 63;
  int g = blockIdx.x*4 + wid;          // bh*L + l
  int l = g & (L_SEQ-1), bh = g >> 11;
  int sg = lane >> 3, dg = lane & 7;

  bf16x8 qv = *(const bf16x8*)(Q + (size_t)g*64 + dg*8);
  float qf[8];
  #pragma unroll
  for (int e=0;e<8;e++) qf[e] = bf2f((ushort)qv[e]);

  const int* ir = idx + l*NSAMP;
  int ki[5];
  #pragma unroll
  for (int i=0;i<5;i++) ki[i] = ir[i*8 + sg];
  const ushort* Kb = Km + (size_t)bh*L_SEQ*64;
  bf16x8 kv[5];
  #pragma unroll
  for (int i=0;i<5;i++) kv[i] = *(const bf16x8*)(Kb + (size_t)ki[i]*64 + dg*8);

  float mx = -INFINITY, sm = 0.f;
  #pragma unroll
  for (int i=0;i<5;i++){
    float d = 0.f;
    #pragma unroll
    for (int e=0;e<8;e++) d = fmaf(qf[e], bf2f((ushort)kv[i][e]), d);
    #pragma unroll
    for (int off=1; off<8; off<<=1) d += __shfl_xor(d, off);
    mx = fmaxf(mx, d);
    sm += d;
  }
  #pragma unroll
  for (int off=1; off<64; off<<=1){
    mx = fmaxf(mx, __shfl_xor(mx, off));
    sm += __shfl_xor(sm, off);
  }
  if (lane==0) M[g] = mx - sm * (1.f/(8.f*(float)NSAMP));
}

// ---------------- top-40: two-level parallel selection on unique u64 keys ----------------
// key = (fkey(value) << 32) | ~index  — order matches lax.top_k (value desc, index asc).
// Mtop order is irrelevant downstream (scatter with distinct indices).
__global__ __launch_bounds__(64) void k_topk1(const float* __restrict__ M,
                                              unsigned long long* __restrict__ cand){
  int blk = blockIdx.x;               // bh*8 + slice
  int bh = blk >> 3, sl = blk & 7;
  int lane = threadIdx.x;
  const float* Mr = M + (size_t)bh*L_SEQ + sl*256;
  unsigned long long k[4];
  #pragma unroll
  for (int s=0; s<4; s++){
    int j = s*64 + lane;
    int gidx = sl*256 + j;
    k[s] = ((unsigned long long)fkey(Mr[j]) << 32) | (unsigned)(~gidx);
  }
  for (int sel=0; sel<NSAMP; sel++){
    unsigned long long best = k[0];
    #pragma unroll
    for (int s=1; s<4; s++) best = (k[s] > best) ? k[s] : best;
    #pragma unroll
    for (int off=1; off<64; off<<=1){
      unsigned long long o = __shfl_xor(best, off);
      best = (o > best) ? o : best;
    }
    #pragma unroll
    for (int s=0; s<4; s++) if (k[s] == best) k[s] = 0ull;
    if (lane == 0) cand[(size_t)blk*NSAMP + sel] = best;
  }
}

__global__ __launch_bounds__(64) void k_topk2(const unsigned long long* __restrict__ cand,
                                              int* __restrict__ Mtop){
  int bh = blockIdx.x, lane = threadIdx.x;
  const unsigned long long* cb = cand + (size_t)bh*8*NSAMP;   // 320 candidates
  unsigned long long k[5];
  #pragma unroll
  for (int s=0; s<5; s++) k[s] = cb[s*64 + lane];
  for (int sel=0; sel<NSAMP; sel++){
    unsigned long long best = k[0];
    #pragma unroll
    for (int s=1; s<5; s++) best = (k[s] > best) ? k[s] : best;
    #pragma unroll
    for (int off=1; off<64; off<<=1){
      unsigned long long o = __shfl_xor(best, off);
      best = (o > best) ? o : best;
    }
    #pragma unroll
    for (int s=0; s<5; s++) if (k[s] == best) k[s] = 0ull;
    if (lane == 0) Mtop[bh*NSAMP + sel] = (int)(~(unsigned)best & (L_SEQ-1));
  }
}

// ---------------- ctx init = broadcast mean V ----------------
__global__ __launch_bounds__(256) void k_ctxfill(const float* __restrict__ vmean, ushort* __restrict__ ctx){
  int i = blockIdx.x*256 + threadIdx.x;
  int c = i & (DM-1);
  int b = i >> 20;
  int h = c >> 6, d = c & 63;
  ctx[i] = f2bf(vmean[((b<<3)+h)*64 + d]);
}

// ---------------- MFMA flash attention, stage 1: per-chunk partials ----------------
__global__ __launch_bounds__(256) void k_attn1(const ushort* __restrict__ Q, const ushort* __restrict__ K,
    const ushort* __restrict__ V, const int* __restrict__ Mtop,
    float* __restrict__ pm, float* __restrict__ ps, float* __restrict__ pO){
  int bid = blockIdx.x;
  int xcd = bid & 7, idx = bid >> 3;
  int bh = xcd*4 + (idx & 3), ch = idx >> 2;
  int l0 = ch * CKEY;
  int t = threadIdx.x, lane = t & 63, w = t >> 6;

  __shared__ ushort Qs[48][64];
  __shared__ ushort Ks[CKEY][64];
  __shared__ ushort Vs[CKEY][66];
  __shared__ ushort Ps[48][136];
  __shared__ float rmax[4][48];
  __shared__ float rsum[4][48];
  __shared__ float Oacc[48][64];
  __shared__ int qidx[48];

  if (t < 40) qidx[t] = Mtop[bh*NSAMP + t];
  const ushort* Kb = K + ((size_t)bh*L_SEQ + l0)*64;
  #pragma unroll
  for (int i=0;i<4;i++){
    int e = i*256 + t;
    __builtin_amdgcn_global_load_lds(
      (const __attribute__((address_space(1))) void*)(Kb + (size_t)e*8),
      (__attribute__((address_space(3))) void*)(&Ks[0][0] + (size_t)e*8), 16, 0, 0);
  }
  __syncthreads();

  const ushort* Qb = Q + (size_t)bh*L_SEQ*64;
  {
    int row = t >> 3, seg = t & 7;
    bf16x8 qv = *(const bf16x8*)(Qb + (size_t)qidx[row]*64 + seg*8);
    *(bf16x8*)&Qs[row][seg*8] = qv;
    if (t < 128){
      int r2 = 32 + (t>>3);
      bf16x8 z = (bf16x8){0,0,0,0,0,0,0,0};
      if (r2 < 40) z = *(const bf16x8*)(Qb + (size_t)qidx[r2]*64 + (t&7)*8);
      *(bf16x8*)&Qs[r2][(t&7)*8] = z;
    }
  }
  const ushort* Vb = V + ((size_t)bh*L_SEQ + l0)*64;
  #pragma unroll
  for (int i=0;i<4;i++){
    int e = i*256 + t;
    int row = e >> 3, seg = e & 7;
    bf16x8 vv = *(const bf16x8*)(Vb + (size_t)e*8);
    *(bf16x8*)&Vs[row][seg*8] = vv;
  }
  __syncthreads();

  for (int i=t; i<48*64; i+=256) ((float*)Oacc)[i] = 0.f;

  f32x4 sa[3][2];
  #pragma unroll
  for (int i=0;i<3;i++) for (int j=0;j<2;j++) sa[i][j] = (f32x4){0.f,0.f,0.f,0.f};
  #pragma unroll
  for (int ks=0; ks<2; ks++){
    int ko = ks*32 + (lane>>4)*8;
    bf16x8 af[3], bf[2];
    #pragma unroll
    for (int i=0;i<3;i++) af[i] = *(const bf16x8*)&Qs[i*16 + (lane&15)][ko];
    #pragma unroll
    for (int j=0;j<2;j++) bf[j] = *(const bf16x8*)&Ks[w*32 + j*16 + (lane&15)][ko];
    #pragma unroll
    for (int i=0;i<3;i++)
      #pragma unroll
      for (int j=0;j<2;j++)
        sa[i][j] = __builtin_amdgcn_mfma_f32_16x16x32_bf16(af[i], bf[j], sa[i][j], 0,0,0);
  }
  #pragma unroll
  for (int i=0;i<3;i++)
    #pragma unroll
    for (int j=0;j<2;j++)
      #pragma unroll
      for (int jj=0;jj<4;jj++) sa[i][j][jj] *= 0.125f;
  #pragma unroll
  for (int i=0;i<3;i++){
    #pragma unroll
    for (int jj=0;jj<4;jj++){
      float mx = fmaxf(sa[i][0][jj], sa[i][1][jj]);
      #pragma unroll
      for (int off=1; off<16; off<<=1) mx = fmaxf(mx, __shfl_xor(mx, off));
      if ((lane&15)==0) rmax[w][i*16 + (lane>>4)*4 + jj] = mx;
    }
  }
  __syncthreads();
  #pragma unroll
  for (int i=0;i<3;i++){
    #pragma unroll
    for (int jj=0;jj<4;jj++){
      int row = i*16 + (lane>>4)*4 + jj;
      float m = fmaxf(fmaxf(rmax[0][row], rmax[1][row]), fmaxf(rmax[2][row], rmax[3][row]));
      float p0 = __expf(sa[i][0][jj] - m);
      float p1 = __expf(sa[i][1][jj] - m);
      Ps[row][w*32 + (lane&15)]      = f2bf(p0);
      Ps[row][w*32 + 16 + (lane&15)] = f2bf(p1);
      float sm = p0 + p1;
      #pragma unroll
      for (int off=1; off<16; off<<=1) sm += __shfl_xor(sm, off);
      if ((lane&15)==0) rsum[w][row] = sm;
    }
  }
  __syncthreads();

  f32x4 oa[3][4];
  #pragma unroll
  for (int i=0;i<3;i++) for (int j=0;j<4;j++) oa[i][j] = (f32x4){0.f,0.f,0.f,0.f};
  {
    bf16x8 pa[3], vb[4];
    int kbase = w*32 + (lane>>4)*8;
    #pragma unroll
    for (int i=0;i<3;i++) pa[i] = *(const bf16x8*)&Ps[i*16 + (lane&15)][kbase];
    #pragma unroll
    for (int j=0;j<4;j++){
      #pragma unroll
      for (int e=0;e<8;e++) vb[j][e] = (short)Vs[kbase + e][j*16 + (lane&15)];
    }
    #pragma unroll
    for (int i=0;i<3;i++)
      #pragma unroll
      for (int j=0;j<4;j++)
        oa[i][j] = __builtin_amdgcn_mfma_f32_16x16x32_bf16(pa[i], vb[j], oa[i][j], 0,0,0);
  }
  #pragma unroll
  for (int ww=0; ww<4; ww++){
    if (w == ww){
      #pragma unroll
      for (int i=0;i<3;i++)
        #pragma unroll
        for (int j=0;j<4;j++)
          #pragma unroll
          for (int jj=0;jj<4;jj++)
            Oacc[i*16 + (lane>>4)*4 + jj][j*16 + (lane&15)] += oa[i][j][jj];
    }
    __syncthreads();
  }

  size_t base = ((size_t)bh*PARTC + ch);
  if (t < 40){
    float m = fmaxf(fmaxf(rmax[0][t], rmax[1][t]), fmaxf(rmax[2][t], rmax[3][t]));
    pm[base*40 + t] = m;
    ps[base*40 + t] = rsum[0][t]+rsum[1][t]+rsum[2][t]+rsum[3][t];
  }
  {
    int row = t >> 3, d0 = (t&7)*8;
    float* dst = pO + (base*48 + row)*64 + d0;
    #pragma unroll
    for (int e=0;e<8;e++) dst[e] = Oacc[row][d0+e];
    if (t < 64){
      int r2 = 32 + (t>>3);
      float* dst2 = pO + (base*48 + r2)*64 + d0;
      #pragma unroll
      for (int e=0;e<8;e++) dst2[e] = Oacc[r2][d0+e];
    }
  }
}

// ---------------- flash attention, stage 2: combine chunks, scatter to ctx ----------------
__global__ __launch_bounds__(256) void k_attn2(const float* __restrict__ pm, const float* __restrict__ ps,
    const float* __restrict__ pO, const int* __restrict__ Mtop, ushort* __restrict__ ctx){
  int bh = blockIdx.x, b = bh >> 3, h = bh & 7;
  int t = threadIdx.x;
  __shared__ float wch[PARTC][40];
  __shared__ float inv_s[40];
  __shared__ int qidx[40];
  if (t < 40){
    qidx[t] = Mtop[bh*NSAMP + t];
    float m = -INFINITY;
    #pragma unroll
    for (int c=0;c<PARTC;c++) m = fmaxf(m, pm[((size_t)bh*PARTC + c)*40 + t]);
    float s = 0.f;
    #pragma unroll
    for (int c=0;c<PARTC;c++){
      float wc = __expf(pm[((size_t)bh*PARTC + c)*40 + t] - m);
      wch[c][t] = wc;
      s += wc * ps[((size_t)bh*PARTC + c)*40 + t];
    }
    inv_s[t] = 1.f / s;
  }
  __syncthreads();
  #pragma unroll
  for (int iter=0; iter<2; iter++){
    int row = iter*32 + (t>>3);
    if (row < 40){
      int d0 = (t&7)*8;
      float o[8] = {0.f,0.f,0.f,0.f,0.f,0.f,0.f,0.f};
      for (int c=0;c<PARTC;c++){
        const float* pp = pO + (((size_t)bh*PARTC + c)*48 + row)*64 + d0;
        float wc = wch[c][row];
        float4 a = *(const float4*)pp, b4 = *(const float4*)(pp+4);
        o[0]=fmaf(wc,a.x,o[0]); o[1]=fmaf(wc,a.y,o[1]); o[2]=fmaf(wc,a.z,o[2]); o[3]=fmaf(wc,a.w,o[3]);
        o[4]=fmaf(wc,b4.x,o[4]); o[5]=fmaf(wc,b4.y,o[5]); o[6]=fmaf(wc,b4.z,o[6]); o[7]=fmaf(wc,b4.w,o[7]);
      }
      float is = inv_s[row];
      bf16x8 wv;
      #pragma unroll
      for (int e=0;e<8;e++) wv[e] = (short)f2bf(o[e]*is);
      *(bf16x8*)(ctx + ((size_t)b*L_SEQ + qidx[row])*DM + h*64 + d0) = wv;
    }
  }
}

// ---------------- LayerNorm: one wave per row ----------------
__global__ __launch_bounds__(256) void k_ln(float* __restrict__ x,
    const float* __restrict__ g, const float* __restrict__ b,
    ushort* __restrict__ xb){
  int row = blockIdx.x*4 + (threadIdx.x>>6);
  int lane = threadIdx.x & 63;
  float* xr = x + (size_t)row*DM + lane*8;
  float4 v0 = *(const float4*)(xr);
  float4 v1 = *(const float4*)(xr + 4);
  float s = v0.x+v0.y+v0.z+v0.w+v1.x+v1.y+v1.z+v1.w;
  #pragma unroll
  for (int off=1; off<64; off<<=1) s += __shfl_xor(s, off);
  float mu = s * (1.f/(float)DM);
  float d0=v0.x-mu, d1=v0.y-mu, d2=v0.z-mu, d3=v0.w-mu;
  float d4=v1.x-mu, d5=v1.y-mu, d6=v1.z-mu, d7=v1.w-mu;
  float q = d0*d0+d1*d1+d2*d2+d3*d3+d4*d4+d5*d5+d6*d6+d7*d7;
  #pragma unroll
  for (int off=1; off<64; off<<=1) q += __shfl_xor(q, off);
  float r = rsqrtf(q * (1.f/(float)DM) + 1e-5f);
  float4 g0 = *(const float4*)(g + lane*8);
  float4 g1 = *(const float4*)(g + lane*8 + 4);
  float4 b0 = *(const float4*)(b + lane*8);
  float4 b1 = *(const float4*)(b + lane*8 + 4);
  float o0=d0*r*g0.x+b0.x, o1=d1*r*g0.y+b0.y, o2=d2*r*g0.z+b0.z, o3=d3*r*g0.w+b0.w;
  float o4=d4*r*g1.x+b1.x, o5=d5*r*g1.y+b1.y, o6=d6*r*g1.z+b1.z, o7=d7*r*g1.w+b1.w;
  *(float4*)(xr)     = (float4){o0,o1,o2,o3};
  *(float4*)(xr + 4) = (float4){o4,o5,o6,o7};
  if (xb){
    bf16x8 w;
    w[0]=(short)f2bf(o0); w[1]=(short)f2bf(o1); w[2]=(short)f2bf(o2); w[3]=(short)f2bf(o3);
    w[4]=(short)f2bf(o4); w[5]=(short)f2bf(o5); w[6]=(short)f2bf(o6); w[7]=(short)f2bf(o7);
    *(bf16x8*)(xb + (size_t)row*DM + lane*8) = w;
  }
}

// ---------------- final logits ----------------
__global__ __launch_bounds__(64) void k_logits(const float* __restrict__ x, const float* __restrict__ embW,
                                               float* __restrict__ out){
  int bid = blockIdx.x;
  int b = bid / NGRID, g = bid - b*NGRID;
  const float* xr = x + ((size_t)b*L_SEQ + (L_SEQ-1))*DM;
  const float* er = embW + (size_t)g*DM;
  int lane = threadIdx.x;
  float s = 0.f;
  for (int d=lane; d<DM; d+=64) s = fmaf(xr[d], er[d], s);
  for (int off=32; off; off>>=1) s += __shfl_xor(s, off);
  if (lane==0) out[bid] = s;
}

extern "C" void kernel_launch(void* const* d_in, const int* in_sizes, int n_in,
                              void* d_out, int out_size, void* d_ws, size_t ws_size,
                              hipStream_t stream) {
  const int*   tok    = (const int*)d_in[0];
  const float* x_enc  = (const float*)d_in[1];
  const float* x_mark = (const float*)d_in[2];
  const float* embW   = (const float*)d_in[3];
  const float* convW  = (const float*)d_in[4];
  const float* timeW  = (const float*)d_in[5];
  const float* timeb  = (const float*)d_in[6];
  const float* Wq = (const float*)d_in[7];  const float* bq = (const float*)d_in[8];
  const float* Wk = (const float*)d_in[9];  const float* bk = (const float*)d_in[10];
  const float* Wv = (const float*)d_in[11]; const float* bv = (const float*)d_in[12];
  const float* Wo = (const float*)d_in[13]; const float* bo = (const float*)d_in[14];
  const float* ln1g = (const float*)d_in[15]; const float* ln1b = (const float*)d_in[16];
  const float* ln2g = (const float*)d_in[17]; const float* ln2b = (const float*)d_in[18];
  const float* f1W = (const float*)d_in[19]; const float* f1b = (const float*)d_in[20];
  const float* f2W = (const float*)d_in[21]; const float* f2b = (const float*)d_in[22];
  const float* nrmg = (const float*)d_in[23]; const float* nrmb = (const float*)d_in[24];
  float* out = (float*)d_out;

  char* ws = (char*)d_ws;
  float*  x    = (float*) (ws);                       // 16 MB f32 residual
  ushort* xb   = (ushort*)(ws + ((size_t)16<<20));    //  8 MB bf16 GEMM input
  ushort* q    = (ushort*)(ws + ((size_t)24<<20));    //  8 MB (B,H,L,64); k,v follow
  ushort* kbuf = (ushort*)(ws + ((size_t)32<<20));
  ushort* vbuf = (ushort*)(ws + ((size_t)40<<20));
  ushort* ctx  = (ushort*)(ws + ((size_t)48<<20));    //  8 MB
  ushort* hbuf = (ushort*)(ws + ((size_t)24<<20));    // 32 MB, overlays q/k/v/ctx
  ushort* wt   = (ushort*)(ws + ((size_t)56<<20));    // 12 MB bf16 weights^T
  float*  Mbuf = (float*) (ws + ((size_t)69<<20));
  int*    Mtop = (int*)   (ws + ((size_t)70<<20));
  int*    sidx = (int*)   (ws + ((size_t)71<<20));
  float*  vmean= (float*) (ws + ((size_t)72<<20));
  float*  bcat = (float*) (ws + ((size_t)73<<20));
  float*  part = (float*) (ws + ((size_t)74<<20));
  float*  pO   = (float*) (ws + ((size_t)75<<20));    // 6.3 MB
  float*  pmb  = (float*) (ws + ((size_t)82<<20));
  float*  psb  = (float*) (ws + ((size_t)82<<20) + 102400);
  unsigned long long* cand = (unsigned long long*)(ws + ((size_t)83<<20));  // 32*320 u64 = 80 KB

  const int Mrows = NB*L_SEQ;   // 8192
  const size_t WQT=0, WOT=786432, F1T=1048576, F2T=2097152, LSTR=3145728;

  k_prep<<<6465, 256, 0, stream>>>(Wq, Wk, Wv, Wo, f1W, f2W, bq, bk, bv, wt, bcat, sidx);
  k_embed<<<NB*L_SEQ, 256, 0, stream>>>(tok, x_enc, x_mark, embW, convW, timeW, timeb, x, xb);

  for (int l=0; l<2; l++){
    size_t b5 = (size_t)l*DM;
    ushort* wl = wt + (size_t)l*LSTR;

    k_mgemm<<<dim3(1536/64, Mrows/64), 256, 0, stream>>>(xb, wl+WQT, bcat+l*1536, nullptr, q, Mrows, 1536, DM, MG_QKV);
    k_vmean1<<<NB*NH*32, 256, 0, stream>>>(vbuf, part);
    k_vmean2<<<NB*NH, 64, 0, stream>>>(part, vmean);
    k_mscore<<<NB*NH*L_SEQ/4, 256, 0, stream>>>(q, kbuf, sidx, Mbuf);
    k_topk1<<<NB*NH*8, 64, 0, stream>>>(Mbuf, cand);
    k_topk2<<<NB*NH, 64, 0, stream>>>(cand, Mtop);
    k_ctxfill<<<(NB*L_SEQ*DM)/256, 256, 0, stream>>>(vmean, ctx);
    k_attn1<<<NB*NH*PARTC, 256, 0, stream>>>(q, kbuf, vbuf, Mtop, pmb, psb, pO);
    k_attn2<<<NB*NH, 256, 0, stream>>>(pmb, psb, pO, Mtop, ctx);
    k_mgemm<<<dim3(DM/64, Mrows/64), 256, 0, stream>>>(ctx, wl+WOT, bo+b5, x, nullptr, Mrows, DM, DM, MG_ADD);
    k_ln<<<Mrows/4, 256, 0, stream>>>(x, ln1g+b5, ln1b+b5, xb);
    k_mgemm<<<dim3(DFF/64, Mrows/64), 256, 0, stream>>>(xb, wl+F1T, f1b + (size_t)l*DFF, nullptr, hbuf, Mrows, DFF, DM, MG_GELU_BF16);
    k_mgemm<<<dim3(DM/64, Mrows/64), 256, 0, stream>>>(hbuf, wl+F2T, f2b+b5, x, nullptr, Mrows, DM, DFF, MG_ADD);
    k_ln<<<Mrows/4, 256, 0, stream>>>(x, ln2g+b5, ln2b+b5, xb);
  }
  k_ln<<<Mrows/4, 256, 0, stream>>>(x, nrmg, nrmb, nullptr);
  k_logits<<<NB*NGRID, 64, 0, stream>>>(x, embW, out);
}